// Round 3
// baseline (1078.926 us; speedup 1.0000x reference)
//
#include <hip/hip_runtime.h>
#include <hip/hip_bf16.h>

// Problem constants (from reference)
#define N_NODES 50000
#define N_EDGES 640000
#define F_IN 64
#define EDGE_DIM 16
#define HID 128
#define N_LAYERS 3
#define NUM_GRAPHS 64
#define BN_EPS 1e-5f

// bf16 <-> f32 helpers (manual, RNE on pack)
__device__ __forceinline__ float bfl(unsigned int u) {
    unsigned int v = u << 16; float f; __builtin_memcpy(&f, &v, 4); return f;
}
__device__ __forceinline__ float bfh(unsigned int u) {
    unsigned int v = u & 0xffff0000u; float f; __builtin_memcpy(&f, &v, 4); return f;
}
__device__ __forceinline__ unsigned int f2bf(float f) {
    unsigned int v; __builtin_memcpy(&v, &f, 4);
    v += 0x7fffu + ((v >> 16) & 1u);
    return v >> 16;
}
__device__ __forceinline__ unsigned int pack2(float lo, float hi) {
    return f2bf(lo) | (f2bf(hi) << 16);
}

// ---------------------------------------------------------------------------
// CSR build: histogram -> block reduce -> scan of block sums -> block scan ->
// bucket fill. row_ptr doubles as the degree array during the histogram.
// ---------------------------------------------------------------------------
__global__ void k_hist(const int* __restrict__ dst, int* __restrict__ deg) {
    int e = blockIdx.x * 256 + threadIdx.x;   // grid exact: 2500*256 = 640000
    atomicAdd(&deg[dst[e]], 1);
}

__global__ void k_blockred(const int* __restrict__ deg, int* __restrict__ bsums) {
    __shared__ int s[256];
    int i = blockIdx.x * 256 + threadIdx.x;
    int v = (i < N_NODES) ? deg[i] : 0;
    s[threadIdx.x] = v;
    __syncthreads();
    for (int off = 128; off > 0; off >>= 1) {
        if (threadIdx.x < off) s[threadIdx.x] += s[threadIdx.x + off];
        __syncthreads();
    }
    if (threadIdx.x == 0) bsums[blockIdx.x] = s[0];
}

__global__ void k_scan_bsums(int* __restrict__ bsums, int nb) {
    if (threadIdx.x == 0) {
        int run = 0;
        for (int i = 0; i < nb; ++i) { int v = bsums[i]; bsums[i] = run; run += v; }
    }
}

__global__ void k_scan_blocks(int* __restrict__ deg_rowptr, const int* __restrict__ bsums,
                              int* __restrict__ cursor) {
    __shared__ int s[256];
    int tid = threadIdx.x;
    int i = blockIdx.x * 256 + tid;
    int v = (i < N_NODES) ? deg_rowptr[i] : 0;
    s[tid] = v;
    __syncthreads();
    for (int off = 1; off < 256; off <<= 1) {
        int t = 0;
        if (tid >= off) t = s[tid - off];
        __syncthreads();
        s[tid] += t;
        __syncthreads();
    }
    int excl = s[tid] - v + bsums[blockIdx.x];
    if (i < N_NODES) {
        deg_rowptr[i] = excl;
        cursor[i] = excl;
    }
    if (i == N_NODES - 1) deg_rowptr[N_NODES] = N_EDGES;
}

__global__ void k_fill(const int* __restrict__ dst, int* __restrict__ cursor,
                       int* __restrict__ elist) {
    int e = blockIdx.x * 256 + threadIdx.x;   // exact
    int p = atomicAdd(&cursor[dst[e]], 1);
    elist[p] = e;
}

// ---------------------------------------------------------------------------
// Shared GEMM micro-kernel: 64x128 block tile, 256 threads, thread = (tr,tc),
// TM=4 rows strided 16, TN=8 cols as two float4 groups (tc*4 and 64+tc*4).
// ---------------------------------------------------------------------------
template <int LDA>
__device__ __forceinline__ void micro32(const float* __restrict__ As,
                                        const float* __restrict__ Bs,
                                        int tr, int tc4, int koff,
                                        float acc[4][8]) {
#pragma unroll
    for (int k4 = 0; k4 < 32; k4 += 4) {
        float4 a4[4];
#pragma unroll
        for (int i = 0; i < 4; ++i)
            a4[i] = *(const float4*)&As[(tr + 16 * i) * LDA + koff + k4];
#pragma unroll
        for (int kk = 0; kk < 4; ++kk) {
            const float4 b0v = *(const float4*)&Bs[(k4 + kk) * 132 + tc4];
            const float4 b1v = *(const float4*)&Bs[(k4 + kk) * 132 + 64 + tc4];
#pragma unroll
            for (int i = 0; i < 4; ++i) {
                const float av = ((const float*)&a4[i])[kk];
                acc[i][0] = fmaf(av, b0v.x, acc[i][0]);
                acc[i][1] = fmaf(av, b0v.y, acc[i][1]);
                acc[i][2] = fmaf(av, b0v.z, acc[i][2]);
                acc[i][3] = fmaf(av, b0v.w, acc[i][3]);
                acc[i][4] = fmaf(av, b1v.x, acc[i][4]);
                acc[i][5] = fmaf(av, b1v.y, acc[i][5]);
                acc[i][6] = fmaf(av, b1v.z, acc[i][6]);
                acc[i][7] = fmaf(av, b1v.w, acc[i][7]);
            }
        }
    }
}

// ---------------------------------------------------------------------------
// Encoder: hb = bf16(x @ enc_W + enc_b)   (M=50000, K=64, N=128)
// ---------------------------------------------------------------------------
__global__ __launch_bounds__(256) void k_enc(const float* __restrict__ x,
                                             const float* __restrict__ W,
                                             const float* __restrict__ b,
                                             unsigned short* __restrict__ hb) {
    __shared__ float As[64 * 68];
    __shared__ float Bs[32 * 132];
    const int tid = threadIdx.x;
    const int row0 = blockIdx.x * 64;
#pragma unroll
    for (int i = 0; i < 4; ++i) {
        int idx = i * 1024 + tid * 4;
        int r = idx >> 6, c = idx & 63;
        float4 v = make_float4(0.f, 0.f, 0.f, 0.f);
        if (row0 + r < N_NODES) v = *(const float4*)&x[(row0 + r) * F_IN + c];
        *(float4*)&As[r * 68 + c] = v;
    }
    float acc[4][8];
#pragma unroll
    for (int i = 0; i < 4; ++i)
#pragma unroll
        for (int j = 0; j < 8; ++j) acc[i][j] = 0.f;

    const int tr = tid >> 4, tc4 = (tid & 15) * 4;
    for (int kc = 0; kc < 2; ++kc) {
        __syncthreads();
#pragma unroll
        for (int i = 0; i < 4; ++i) {
            int idx = i * 1024 + tid * 4;
            int r = idx >> 7, c = idx & 127;
            *(float4*)&Bs[r * 132 + c] = *(const float4*)&W[(kc * 32 + r) * HID + c];
        }
        __syncthreads();
        micro32<68>(As, Bs, tr, tc4, kc * 32, acc);
    }
    const float4 bb0 = *(const float4*)&b[tc4];
    const float4 bb1 = *(const float4*)&b[64 + tc4];
#pragma unroll
    for (int i = 0; i < 4; ++i) {
        int r = row0 + tr + 16 * i;
        if (r < N_NODES) {
            unsigned int p0 = pack2(acc[i][0] + bb0.x, acc[i][1] + bb0.y);
            unsigned int p1 = pack2(acc[i][2] + bb0.z, acc[i][3] + bb0.w);
            unsigned int p2 = pack2(acc[i][4] + bb1.x, acc[i][5] + bb1.y);
            unsigned int p3 = pack2(acc[i][6] + bb1.z, acc[i][7] + bb1.w);
            *(uint2*)&hb[r * HID + tc4] = make_uint2(p0, p1);
            *(uint2*)&hb[r * HID + 64 + tc4] = make_uint2(p2, p3);
        }
    }
}

// ---------------------------------------------------------------------------
// GINE aggregation (gather-style, no float atomics):
// z[n] = h[n] + sum_{e: dst(e)=n} relu(h[src(e)] + edge_attr[e] @ We + be)
// One wave per node, bf16 h gathers, 4-edge groups with deep MLP:
// per group the wave issues ~21 independent loads then computes ~190 VALU.
// ---------------------------------------------------------------------------
#define EFMA2(AV, J)                                  \
    ef.x = fmaf((AV), w[J].x, ef.x);                  \
    ef.y = fmaf((AV), w[J].y, ef.y);

#define LOAD4(g, out) {                               \
    const int p_ = base + 4 * (g);                    \
    out[0] = elist[min(p_, last)];                    \
    out[1] = elist[min(p_ + 1, last)];                \
    out[2] = elist[min(p_ + 2, last)];                \
    out[3] = elist[min(p_ + 3, last)]; }

__global__ __launch_bounds__(256) void k_agg(const unsigned int* __restrict__ hb32,
                                             const int* __restrict__ esrc,
                                             const float* __restrict__ eattr,
                                             const float* __restrict__ We,
                                             const float* __restrict__ be,
                                             const int* __restrict__ row_ptr,
                                             const int* __restrict__ elist,
                                             float* __restrict__ z) {
    const int lane = threadIdx.x & 63;
    const int f2 = lane * 2;                  // feature pair base (0..126)
    const int wv = threadIdx.x >> 6;          // wave in block (0..3)
    float2 w[16];
#pragma unroll
    for (int j = 0; j < 16; ++j) w[j] = *(const float2*)&We[j * HID + f2];
    const float2 eb = *(const float2*)&be[f2];

    const int n = blockIdx.x * 4 + wv;        // grid exact: 12500*4 = 50000
    const int base = row_ptr[n];
    const int end = row_ptr[n + 1];
    const int deg = end - base;

    const unsigned int hself = hb32[n * 64 + lane];
    float2 acc = make_float2(bfl(hself), bfh(hself));

    if (deg > 0) {
        const int last = end - 1;
        const int G = (deg + 3) >> 2;
        int eidC[4], eidN[4], srcC[4];
        float4 ea[4][4];
        unsigned int hu[4];
        // prologue: indices for groups 0 and 1, data for group 0
        LOAD4(0, eidC);
        LOAD4(1, eidN);
#pragma unroll
        for (int j = 0; j < 4; ++j) srcC[j] = esrc[eidC[j]];
#pragma unroll
        for (int j = 0; j < 4; ++j) {
            ea[j][0] = *(const float4*)&eattr[eidC[j] * EDGE_DIM];
            ea[j][1] = *(const float4*)&eattr[eidC[j] * EDGE_DIM + 4];
            ea[j][2] = *(const float4*)&eattr[eidC[j] * EDGE_DIM + 8];
            ea[j][3] = *(const float4*)&eattr[eidC[j] * EDGE_DIM + 12];
            hu[j] = hb32[srcC[j] * 64 + lane];
        }
        for (int g = 0; g < G; ++g) {
            // prefetch next group's srcs + the group-after-next eids (cheap,
            // issued before compute so they fly during the FMA burst)
            int srcN[4], eidNN[4];
            const bool more = (g + 1) < G;
            if (more) {
#pragma unroll
                for (int j = 0; j < 4; ++j) srcN[j] = esrc[eidN[j]];
                LOAD4(g + 2, eidNN);
            }
            // compute group g (mask trailing edges; deg is wave-uniform)
            const int rem = deg - 4 * g;
#pragma unroll
            for (int j = 0; j < 4; ++j) {
                if (j < rem) {
                    const float4 a0 = ea[j][0], a1 = ea[j][1];
                    const float4 a2 = ea[j][2], a3 = ea[j][3];
                    float2 ef = eb;
                    EFMA2(a0.x, 0)  EFMA2(a0.y, 1)  EFMA2(a0.z, 2)  EFMA2(a0.w, 3)
                    EFMA2(a1.x, 4)  EFMA2(a1.y, 5)  EFMA2(a1.z, 6)  EFMA2(a1.w, 7)
                    EFMA2(a2.x, 8)  EFMA2(a2.y, 9)  EFMA2(a2.z, 10) EFMA2(a2.w, 11)
                    EFMA2(a3.x, 12) EFMA2(a3.y, 13) EFMA2(a3.z, 14) EFMA2(a3.w, 15)
                    acc.x += fmaxf(bfl(hu[j]) + ef.x, 0.f);
                    acc.y += fmaxf(bfh(hu[j]) + ef.y, 0.f);
                }
            }
            if (more) {
                // issue data for group g+1 (srcN issued ~a full FMA burst ago)
#pragma unroll
                for (int j = 0; j < 4; ++j) {
                    ea[j][0] = *(const float4*)&eattr[eidN[j] * EDGE_DIM];
                    ea[j][1] = *(const float4*)&eattr[eidN[j] * EDGE_DIM + 4];
                    ea[j][2] = *(const float4*)&eattr[eidN[j] * EDGE_DIM + 8];
                    ea[j][3] = *(const float4*)&eattr[eidN[j] * EDGE_DIM + 12];
                    hu[j] = hb32[srcN[j] * 64 + lane];
                }
#pragma unroll
                for (int j = 0; j < 4; ++j) eidN[j] = eidNN[j];
            }
        }
    }
    *(float2*)&z[n * HID + f2] = acc;
}

// ---------------------------------------------------------------------------
// Fused node MLP: z2 = relu(z @ W1 + b1) @ W2 + b2, plus per-column
// sum / sumsq partials for BN (atomics into bn[0:128] / bn[128:256]).
// ---------------------------------------------------------------------------
__global__ __launch_bounds__(256) void k_mlp(const float* __restrict__ z,
                                             const float* __restrict__ W1,
                                             const float* __restrict__ b1,
                                             const float* __restrict__ W2,
                                             const float* __restrict__ b2,
                                             float* __restrict__ z2,
                                             float* __restrict__ bn) {
    __shared__ float As[64 * 132];
    __shared__ float Bs[32 * 132];
    __shared__ float red[16 * 128];
    const int tid = threadIdx.x;
    const int row0 = blockIdx.x * 64;
#pragma unroll
    for (int i = 0; i < 8; ++i) {
        int idx = i * 1024 + tid * 4;
        int r = idx >> 7, c = idx & 127;
        float4 v = make_float4(0.f, 0.f, 0.f, 0.f);
        if (row0 + r < N_NODES) v = *(const float4*)&z[(row0 + r) * HID + c];
        *(float4*)&As[r * 132 + c] = v;
    }
    const int tr = tid >> 4, tc4 = (tid & 15) * 4;
    float acc[4][8];
#pragma unroll
    for (int i = 0; i < 4; ++i)
#pragma unroll
        for (int j = 0; j < 8; ++j) acc[i][j] = 0.f;

    for (int kc = 0; kc < 4; ++kc) {
        __syncthreads();
#pragma unroll
        for (int i = 0; i < 4; ++i) {
            int idx = i * 1024 + tid * 4;
            int r = idx >> 7, c = idx & 127;
            *(float4*)&Bs[r * 132 + c] = *(const float4*)&W1[(kc * 32 + r) * HID + c];
        }
        __syncthreads();
        micro32<132>(As, Bs, tr, tc4, kc * 32, acc);
    }
    {
        const float4 bb0 = *(const float4*)&b1[tc4];
        const float4 bb1 = *(const float4*)&b1[64 + tc4];
        __syncthreads();
#pragma unroll
        for (int i = 0; i < 4; ++i) {
            int rl = tr + 16 * i;
            float4 o0 = make_float4(fmaxf(acc[i][0] + bb0.x, 0.f), fmaxf(acc[i][1] + bb0.y, 0.f),
                                    fmaxf(acc[i][2] + bb0.z, 0.f), fmaxf(acc[i][3] + bb0.w, 0.f));
            float4 o1 = make_float4(fmaxf(acc[i][4] + bb1.x, 0.f), fmaxf(acc[i][5] + bb1.y, 0.f),
                                    fmaxf(acc[i][6] + bb1.z, 0.f), fmaxf(acc[i][7] + bb1.w, 0.f));
            *(float4*)&As[rl * 132 + tc4] = o0;
            *(float4*)&As[rl * 132 + 64 + tc4] = o1;
        }
#pragma unroll
        for (int i = 0; i < 4; ++i)
#pragma unroll
            for (int j = 0; j < 8; ++j) acc[i][j] = 0.f;
    }
    for (int kc = 0; kc < 4; ++kc) {
        __syncthreads();
#pragma unroll
        for (int i = 0; i < 4; ++i) {
            int idx = i * 1024 + tid * 4;
            int r = idx >> 7, c = idx & 127;
            *(float4*)&Bs[r * 132 + c] = *(const float4*)&W2[(kc * 32 + r) * HID + c];
        }
        __syncthreads();
        micro32<132>(As, Bs, tr, tc4, kc * 32, acc);
    }
    const float4 bb0 = *(const float4*)&b2[tc4];
    const float4 bb1 = *(const float4*)&b2[64 + tc4];
    float outv[4][8];
    bool valid[4];
#pragma unroll
    for (int i = 0; i < 4; ++i) {
        valid[i] = (row0 + tr + 16 * i) < N_NODES;
        outv[i][0] = acc[i][0] + bb0.x; outv[i][1] = acc[i][1] + bb0.y;
        outv[i][2] = acc[i][2] + bb0.z; outv[i][3] = acc[i][3] + bb0.w;
        outv[i][4] = acc[i][4] + bb1.x; outv[i][5] = acc[i][5] + bb1.y;
        outv[i][6] = acc[i][6] + bb1.z; outv[i][7] = acc[i][7] + bb1.w;
        if (valid[i]) {
            int r = row0 + tr + 16 * i;
            *(float4*)&z2[r * HID + tc4] = make_float4(outv[i][0], outv[i][1], outv[i][2], outv[i][3]);
            *(float4*)&z2[r * HID + 64 + tc4] = make_float4(outv[i][4], outv[i][5], outv[i][6], outv[i][7]);
        }
    }
    float s[8], sq[8];
#pragma unroll
    for (int j = 0; j < 8; ++j) { s[j] = 0.f; sq[j] = 0.f; }
#pragma unroll
    for (int i = 0; i < 4; ++i) {
        if (valid[i]) {
#pragma unroll
            for (int j = 0; j < 8; ++j) {
                s[j] += outv[i][j];
                sq[j] = fmaf(outv[i][j], outv[i][j], sq[j]);
            }
        }
    }
    __syncthreads();
    *(float4*)&red[tr * 128 + tc4] = make_float4(s[0], s[1], s[2], s[3]);
    *(float4*)&red[tr * 128 + 64 + tc4] = make_float4(s[4], s[5], s[6], s[7]);
    __syncthreads();
    if (tid < 128) {
        float t = 0.f;
#pragma unroll
        for (int r = 0; r < 16; ++r) t += red[r * 128 + tid];
        atomicAdd(&bn[tid], t);
    }
    __syncthreads();
    *(float4*)&red[tr * 128 + tc4] = make_float4(sq[0], sq[1], sq[2], sq[3]);
    *(float4*)&red[tr * 128 + 64 + tc4] = make_float4(sq[4], sq[5], sq[6], sq[7]);
    __syncthreads();
    if (tid < 128) {
        float t = 0.f;
#pragma unroll
        for (int r = 0; r < 16; ++r) t += red[r * 128 + tid];
        atomicAdd(&bn[128 + tid], t);
    }
}

// ---------------------------------------------------------------------------
// BN (batch stats) + ReLU -> bf16 h:  hb = bf16(relu(gamma*(z2-m)*rsqrt(v)+beta))
// ---------------------------------------------------------------------------
__global__ __launch_bounds__(256) void k_bnrelu(const float* __restrict__ z2,
                                                const float* __restrict__ bn,
                                                const float* __restrict__ gamma,
                                                const float* __restrict__ beta,
                                                unsigned short* __restrict__ hb) {
    const int idx = (blockIdx.x * 256 + threadIdx.x) * 4;   // exact: 6250*256*4 = 6.4M
    const int c = idx & 127;
    const float invN = 1.0f / (float)N_NODES;
    float4 v = *(const float4*)&z2[idx];
    float o[4] = {v.x, v.y, v.z, v.w};
#pragma unroll
    for (int k = 0; k < 4; ++k) {
        const float m = bn[c + k] * invN;
        float var = bn[128 + c + k] * invN - m * m;
        var = fmaxf(var, 0.f);
        const float r = rsqrtf(var + BN_EPS);
        o[k] = fmaxf(gamma[c + k] * (o[k] - m) * r + beta[c + k], 0.f);
    }
    *(uint2*)&hb[idx] = make_uint2(pack2(o[0], o[1]), pack2(o[2], o[3]));
}

// ---------------------------------------------------------------------------
// Global add pool (batch is sorted): register accumulate, flush on change.
// ---------------------------------------------------------------------------
__global__ void k_pool(const unsigned short* __restrict__ hb, const int* __restrict__ batch,
                       float* __restrict__ g) {
    const int f = threadIdx.x;            // 128 threads
    const int n0 = blockIdx.x * 128;
    const int nend = min(n0 + 128, N_NODES);
    float acc = 0.f;
    int cur = batch[n0];
    for (int n = n0; n < nend; ++n) {
        const int bb = batch[n];
        if (bb != cur) {
            atomicAdd(&g[cur * HID + f], acc);
            acc = 0.f;
            cur = bb;
        }
        unsigned int u = hb[n * HID + f];
        acc += bfl(u << 16) * 0.f + bfh(u << 16);   // value = bits<<16
    }
    atomicAdd(&g[cur * HID + f], acc);
}

// ---------------------------------------------------------------------------
// Head
// ---------------------------------------------------------------------------
__global__ void k_head1(const float* __restrict__ g, const float* __restrict__ W,
                        const float* __restrict__ b, float* __restrict__ g1) {
    const int idx = blockIdx.x * 256 + threadIdx.x;   // 32*256 = 8192
    const int r = idx >> 7, c = idx & 127;
    float acc = b[c];
    for (int k = 0; k < 128; ++k) acc = fmaf(g[r * HID + k], W[k * HID + c], acc);
    g1[idx] = fmaxf(acc, 0.f);
}

__global__ void k_head2(const float* __restrict__ g1, const float* __restrict__ W,
                        const float* __restrict__ b, float* __restrict__ out) {
    const int idx = threadIdx.x;          // 128
    const int r = idx >> 1, c = idx & 1;
    float acc = b[c];
    for (int k = 0; k < 128; ++k) acc = fmaf(g1[r * HID + k], W[k * 2 + c], acc);
    out[idx] = acc;
}

// ---------------------------------------------------------------------------
// Launch
// ---------------------------------------------------------------------------
extern "C" void kernel_launch(void* const* d_in, const int* in_sizes, int n_in,
                              void* d_out, int out_size, void* d_ws, size_t ws_size,
                              hipStream_t stream) {
    const float* x     = (const float*)d_in[0];
    const int*   ei    = (const int*)d_in[1];
    const float* eattr = (const float*)d_in[2];
    const int*   batch = (const int*)d_in[3];
    const float* encW  = (const float*)d_in[4];
    const float* encb  = (const float*)d_in[5];
    const float* eW    = (const float*)d_in[6];
    const float* eb    = (const float*)d_in[7];
    const float* W1    = (const float*)d_in[8];
    const float* b1    = (const float*)d_in[9];
    const float* W2    = (const float*)d_in[10];
    const float* b2    = (const float*)d_in[11];
    const float* gam   = (const float*)d_in[12];
    const float* bet   = (const float*)d_in[13];
    const float* hW1   = (const float*)d_in[14];
    const float* hb1   = (const float*)d_in[15];
    const float* hW2   = (const float*)d_in[16];
    const float* hb2   = (const float*)d_in[17];
    float* out = (float*)d_out;

    // workspace layout (float-sized slots); total ~67 MB
    float* ws = (float*)d_ws;
    float* z   = ws;                       // 6,400,000
    float* z2  = ws + 6400000;             // 6,400,000
    float* bn  = ws + 12800000;            // 256
    float* g   = ws + 12800256;            // 8,192
    float* g1  = ws + 12808448;            // 8,192
    unsigned short* hb = (unsigned short*)(ws + 12816640);   // 6.4M bf16 = 3.2M floats
    int* row_ptr = (int*)(ws + 16016640);  // 50,001
    int* cursor  = row_ptr + N_NODES + 1;  // 50,000
    int* elist   = cursor + N_NODES;       // 640,000
    int* bsums   = elist + N_EDGES;        // 256

    const int* esrc = ei;
    const int* edst = ei + N_EDGES;

    // CSR build (every call; edge_index is restored before each timed call)
    hipMemsetAsync(row_ptr, 0, (N_NODES + 1) * sizeof(int), stream);
    k_hist<<<N_EDGES / 256, 256, 0, stream>>>(edst, row_ptr);
    k_blockred<<<196, 256, 0, stream>>>(row_ptr, bsums);
    k_scan_bsums<<<1, 64, 0, stream>>>(bsums, 196);
    k_scan_blocks<<<196, 256, 0, stream>>>(row_ptr, bsums, cursor);
    k_fill<<<N_EDGES / 256, 256, 0, stream>>>(edst, cursor, elist);

    // encoder -> bf16 h
    k_enc<<<782, 256, 0, stream>>>(x, encW, encb, hb);

    for (int l = 0; l < N_LAYERS; ++l) {
        k_agg<<<12500, 256, 0, stream>>>((const unsigned int*)hb, esrc, eattr,
                                         eW + l * EDGE_DIM * HID, eb + l * HID,
                                         row_ptr, elist, z);
        hipMemsetAsync(bn, 0, 256 * sizeof(float), stream);
        k_mlp<<<782, 256, 0, stream>>>(z, W1 + l * HID * HID, b1 + l * HID,
                                       W2 + l * HID * HID, b2 + l * HID, z2, bn);
        k_bnrelu<<<6250, 256, 0, stream>>>(z2, bn, gam + l * HID, bet + l * HID, hb);
    }

    hipMemsetAsync(g, 0, NUM_GRAPHS * HID * sizeof(float), stream);
    k_pool<<<391, 128, 0, stream>>>(hb, batch, g);
    k_head1<<<32, 256, 0, stream>>>(g, hW1, hb1, g1);
    k_head2<<<1, 128, 0, stream>>>(g1, hW2, hb2, out);
}

// Round 4
// 848.936 us; speedup vs baseline: 1.2709x; 1.2709x over previous
//
#include <hip/hip_runtime.h>
#include <hip/hip_bf16.h>

// Problem constants (from reference)
#define N_NODES 50000
#define N_EDGES 640000
#define F_IN 64
#define EDGE_DIM 16
#define HID 128
#define N_LAYERS 3
#define NUM_GRAPHS 64
#define BN_EPS 1e-5f

// bf16 <-> f32 helpers (manual, RNE on pack)
__device__ __forceinline__ float bfl(unsigned int u) {
    unsigned int v = u << 16; float f; __builtin_memcpy(&f, &v, 4); return f;
}
__device__ __forceinline__ float bfh(unsigned int u) {
    unsigned int v = u & 0xffff0000u; float f; __builtin_memcpy(&f, &v, 4); return f;
}
__device__ __forceinline__ unsigned int f2bf(float f) {
    unsigned int v; __builtin_memcpy(&v, &f, 4);
    v += 0x7fffu + ((v >> 16) & 1u);
    return v >> 16;
}
__device__ __forceinline__ unsigned int pack2(float lo, float hi) {
    return f2bf(lo) | (f2bf(hi) << 16);
}

// ---------------------------------------------------------------------------
// CSR build: histogram -> block reduce -> scan of block sums -> block scan ->
// bucket fill. row_ptr doubles as the degree array during the histogram.
// ---------------------------------------------------------------------------
__global__ void k_hist(const int* __restrict__ dst, int* __restrict__ deg) {
    int e = blockIdx.x * 256 + threadIdx.x;   // grid exact: 2500*256 = 640000
    atomicAdd(&deg[dst[e]], 1);
}

__global__ void k_blockred(const int* __restrict__ deg, int* __restrict__ bsums) {
    __shared__ int s[256];
    int i = blockIdx.x * 256 + threadIdx.x;
    int v = (i < N_NODES) ? deg[i] : 0;
    s[threadIdx.x] = v;
    __syncthreads();
    for (int off = 128; off > 0; off >>= 1) {
        if (threadIdx.x < off) s[threadIdx.x] += s[threadIdx.x + off];
        __syncthreads();
    }
    if (threadIdx.x == 0) bsums[blockIdx.x] = s[0];
}

__global__ void k_scan_bsums(int* __restrict__ bsums, int nb) {
    if (threadIdx.x == 0) {
        int run = 0;
        for (int i = 0; i < nb; ++i) { int v = bsums[i]; bsums[i] = run; run += v; }
    }
}

__global__ void k_scan_blocks(int* __restrict__ deg_rowptr, const int* __restrict__ bsums,
                              int* __restrict__ cursor) {
    __shared__ int s[256];
    int tid = threadIdx.x;
    int i = blockIdx.x * 256 + tid;
    int v = (i < N_NODES) ? deg_rowptr[i] : 0;
    s[tid] = v;
    __syncthreads();
    for (int off = 1; off < 256; off <<= 1) {
        int t = 0;
        if (tid >= off) t = s[tid - off];
        __syncthreads();
        s[tid] += t;
        __syncthreads();
    }
    int excl = s[tid] - v + bsums[blockIdx.x];
    if (i < N_NODES) {
        deg_rowptr[i] = excl;
        cursor[i] = excl;
    }
    if (i == N_NODES - 1) deg_rowptr[N_NODES] = N_EDGES;
}

__global__ void k_fill(const int* __restrict__ dst, int* __restrict__ cursor,
                       int* __restrict__ elist) {
    int e = blockIdx.x * 256 + threadIdx.x;   // exact
    int p = atomicAdd(&cursor[dst[e]], 1);
    elist[p] = e;
}

// ---------------------------------------------------------------------------
// Edge materialization in CSR order: src_s[p] = esrc[elist[p]],
// eattr_s[p*16..] = eattr[elist[p]*16..]. Kills the index chain in k_agg
// and makes its edge-stream sequential + wave-uniform. Done once, used x3.
// ---------------------------------------------------------------------------
__global__ void k_gather(const int* __restrict__ elist, const int* __restrict__ esrc,
                         const float* __restrict__ eattr,
                         int* __restrict__ src_s, float* __restrict__ eattr_s) {
    const int p = blockIdx.x * 256 + threadIdx.x;   // exact: 2500*256
    const int eid = elist[p];
    src_s[p] = esrc[eid];
    const float4 a0 = *(const float4*)&eattr[eid * EDGE_DIM];
    const float4 a1 = *(const float4*)&eattr[eid * EDGE_DIM + 4];
    const float4 a2 = *(const float4*)&eattr[eid * EDGE_DIM + 8];
    const float4 a3 = *(const float4*)&eattr[eid * EDGE_DIM + 12];
    *(float4*)&eattr_s[p * EDGE_DIM] = a0;
    *(float4*)&eattr_s[p * EDGE_DIM + 4] = a1;
    *(float4*)&eattr_s[p * EDGE_DIM + 8] = a2;
    *(float4*)&eattr_s[p * EDGE_DIM + 12] = a3;
}

// ---------------------------------------------------------------------------
// Shared GEMM micro-kernel: 64x128 block tile, 256 threads, thread = (tr,tc),
// TM=4 rows strided 16, TN=8 cols as two float4 groups (tc*4 and 64+tc*4).
// ---------------------------------------------------------------------------
template <int LDA>
__device__ __forceinline__ void micro32(const float* __restrict__ As,
                                        const float* __restrict__ Bs,
                                        int tr, int tc4, int koff,
                                        float acc[4][8]) {
#pragma unroll
    for (int k4 = 0; k4 < 32; k4 += 4) {
        float4 a4[4];
#pragma unroll
        for (int i = 0; i < 4; ++i)
            a4[i] = *(const float4*)&As[(tr + 16 * i) * LDA + koff + k4];
#pragma unroll
        for (int kk = 0; kk < 4; ++kk) {
            const float4 b0v = *(const float4*)&Bs[(k4 + kk) * 132 + tc4];
            const float4 b1v = *(const float4*)&Bs[(k4 + kk) * 132 + 64 + tc4];
#pragma unroll
            for (int i = 0; i < 4; ++i) {
                const float av = ((const float*)&a4[i])[kk];
                acc[i][0] = fmaf(av, b0v.x, acc[i][0]);
                acc[i][1] = fmaf(av, b0v.y, acc[i][1]);
                acc[i][2] = fmaf(av, b0v.z, acc[i][2]);
                acc[i][3] = fmaf(av, b0v.w, acc[i][3]);
                acc[i][4] = fmaf(av, b1v.x, acc[i][4]);
                acc[i][5] = fmaf(av, b1v.y, acc[i][5]);
                acc[i][6] = fmaf(av, b1v.z, acc[i][6]);
                acc[i][7] = fmaf(av, b1v.w, acc[i][7]);
            }
        }
    }
}

// ---------------------------------------------------------------------------
// Encoder: hb = bf16(x @ enc_W + enc_b)   (M=50000, K=64, N=128)
// ---------------------------------------------------------------------------
__global__ __launch_bounds__(256) void k_enc(const float* __restrict__ x,
                                             const float* __restrict__ W,
                                             const float* __restrict__ b,
                                             unsigned short* __restrict__ hb) {
    __shared__ float As[64 * 68];
    __shared__ float Bs[32 * 132];
    const int tid = threadIdx.x;
    const int row0 = blockIdx.x * 64;
#pragma unroll
    for (int i = 0; i < 4; ++i) {
        int idx = i * 1024 + tid * 4;
        int r = idx >> 6, c = idx & 63;
        float4 v = make_float4(0.f, 0.f, 0.f, 0.f);
        if (row0 + r < N_NODES) v = *(const float4*)&x[(row0 + r) * F_IN + c];
        *(float4*)&As[r * 68 + c] = v;
    }
    float acc[4][8];
#pragma unroll
    for (int i = 0; i < 4; ++i)
#pragma unroll
        for (int j = 0; j < 8; ++j) acc[i][j] = 0.f;

    const int tr = tid >> 4, tc4 = (tid & 15) * 4;
    for (int kc = 0; kc < 2; ++kc) {
        __syncthreads();
#pragma unroll
        for (int i = 0; i < 4; ++i) {
            int idx = i * 1024 + tid * 4;
            int r = idx >> 7, c = idx & 127;
            *(float4*)&Bs[r * 132 + c] = *(const float4*)&W[(kc * 32 + r) * HID + c];
        }
        __syncthreads();
        micro32<68>(As, Bs, tr, tc4, kc * 32, acc);
    }
    const float4 bb0 = *(const float4*)&b[tc4];
    const float4 bb1 = *(const float4*)&b[64 + tc4];
#pragma unroll
    for (int i = 0; i < 4; ++i) {
        int r = row0 + tr + 16 * i;
        if (r < N_NODES) {
            unsigned int p0 = pack2(acc[i][0] + bb0.x, acc[i][1] + bb0.y);
            unsigned int p1 = pack2(acc[i][2] + bb0.z, acc[i][3] + bb0.w);
            unsigned int p2 = pack2(acc[i][4] + bb1.x, acc[i][5] + bb1.y);
            unsigned int p3 = pack2(acc[i][6] + bb1.z, acc[i][7] + bb1.w);
            *(uint2*)&hb[r * HID + tc4] = make_uint2(p0, p1);
            *(uint2*)&hb[r * HID + 64 + tc4] = make_uint2(p2, p3);
        }
    }
}

// ---------------------------------------------------------------------------
// GINE aggregation v4 (gather-style, no float atomics):
// z[n] = h[n] + sum_{e in CSR[n]} relu(h[src_s[p]] + eattr_s[p] @ We + be)
// One wave per node. Scalar (readfirstlane) edge range -> src_s / eattr_s
// loads become wave-uniform (SMEM path); only the h-gather is vector memory.
// Chunk-of-8 double buffer: 8 gathers in flight during ~600 cyc of FMA.
// ---------------------------------------------------------------------------
#define EFMA2(AV, J)                                  \
    ef.x = fmaf((AV), w[J].x, ef.x);                  \
    ef.y = fmaf((AV), w[J].y, ef.y);

__global__ __launch_bounds__(256, 2) void k_agg(const unsigned int* __restrict__ hb32,
                                                const int* __restrict__ src_s,
                                                const float* __restrict__ eattr_s,
                                                const float* __restrict__ We,
                                                const float* __restrict__ be,
                                                const int* __restrict__ row_ptr,
                                                float* __restrict__ z) {
    const int lane = threadIdx.x & 63;
    const int f2 = lane * 2;                  // feature pair base (0..126)
    const int wv = threadIdx.x >> 6;          // wave in block (0..3)
    float2 w[16];
#pragma unroll
    for (int j = 0; j < 16; ++j) w[j] = *(const float2*)&We[j * HID + f2];
    const float2 eb = *(const float2*)&be[f2];

    const int n = blockIdx.x * 4 + wv;        // grid exact: 12500*4 = 50000
    const int base = __builtin_amdgcn_readfirstlane(row_ptr[n]);
    const int deg = __builtin_amdgcn_readfirstlane(row_ptr[n + 1]) - base;

    const unsigned int hself = hb32[n * 64 + lane];
    float2 acc = make_float2(bfl(hself), bfh(hself));

    if (deg > 0) {
        const int* sp = src_s + base;                       // uniform, sequential
        const float* ep = eattr_s + (size_t)base * EDGE_DIM; // uniform, sequential
        const int last = deg - 1;
        const int nch = (deg + 7) >> 3;

        // prologue: srcs for chunk 0 -> gathers in flight; srcs for chunk 1
        int srcN[8];
        unsigned int huC[8];
        {
            int s0[8];
#pragma unroll
            for (int j = 0; j < 8; ++j) s0[j] = sp[min(j, last)];
#pragma unroll
            for (int j = 0; j < 8; ++j) huC[j] = hb32[s0[j] * 64 + lane];
        }
#pragma unroll
        for (int j = 0; j < 8; ++j) srcN[j] = sp[min(8 + j, last)];

        for (int c = 0; c < nch; ++c) {
            const bool more = (c + 1) < nch;
            // issue gathers for chunk c+1 (srcs loaded an iteration ago)
            unsigned int huN[8];
            if (more) {
#pragma unroll
                for (int j = 0; j < 8; ++j) huN[j] = hb32[srcN[j] * 64 + lane];
            }
            // prefetch srcs for chunk c+2 (uniform sequential loads)
            int srcNN[8];
            if (c + 2 < nch) {
#pragma unroll
                for (int j = 0; j < 8; ++j) srcNN[j] = sp[min((c + 2) * 8 + j, last)];
            }
            // compute chunk c; eattr loads are uniform sequential (scalar path)
            const int rem = deg - c * 8;      // >= 1, wave-uniform
            const float* epc = ep + (size_t)(c * 8) * EDGE_DIM;
#pragma unroll
            for (int j = 0; j < 8; ++j) {
                if (j < rem) {
                    const float4 a0 = *(const float4*)&epc[j * EDGE_DIM];
                    const float4 a1 = *(const float4*)&epc[j * EDGE_DIM + 4];
                    const float4 a2 = *(const float4*)&epc[j * EDGE_DIM + 8];
                    const float4 a3 = *(const float4*)&epc[j * EDGE_DIM + 12];
                    float2 ef = eb;
                    EFMA2(a0.x, 0)  EFMA2(a0.y, 1)  EFMA2(a0.z, 2)  EFMA2(a0.w, 3)
                    EFMA2(a1.x, 4)  EFMA2(a1.y, 5)  EFMA2(a1.z, 6)  EFMA2(a1.w, 7)
                    EFMA2(a2.x, 8)  EFMA2(a2.y, 9)  EFMA2(a2.z, 10) EFMA2(a2.w, 11)
                    EFMA2(a3.x, 12) EFMA2(a3.y, 13) EFMA2(a3.z, 14) EFMA2(a3.w, 15)
                    acc.x += fmaxf(bfl(huC[j]) + ef.x, 0.f);
                    acc.y += fmaxf(bfh(huC[j]) + ef.y, 0.f);
                }
            }
            // rotate pipeline
            if (more) {
#pragma unroll
                for (int j = 0; j < 8; ++j) { huC[j] = huN[j]; srcN[j] = srcNN[j]; }
            }
        }
    }
    *(float2*)&z[n * HID + f2] = acc;
}

// ---------------------------------------------------------------------------
// Fused node MLP: z2 = relu(z @ W1 + b1) @ W2 + b2, plus per-column
// sum / sumsq partials for BN (atomics into bn[0:128] / bn[128:256]).
// ---------------------------------------------------------------------------
__global__ __launch_bounds__(256) void k_mlp(const float* __restrict__ z,
                                             const float* __restrict__ W1,
                                             const float* __restrict__ b1,
                                             const float* __restrict__ W2,
                                             const float* __restrict__ b2,
                                             float* __restrict__ z2,
                                             float* __restrict__ bn) {
    __shared__ float As[64 * 132];
    __shared__ float Bs[32 * 132];
    __shared__ float red[16 * 128];
    const int tid = threadIdx.x;
    const int row0 = blockIdx.x * 64;
#pragma unroll
    for (int i = 0; i < 8; ++i) {
        int idx = i * 1024 + tid * 4;
        int r = idx >> 7, c = idx & 127;
        float4 v = make_float4(0.f, 0.f, 0.f, 0.f);
        if (row0 + r < N_NODES) v = *(const float4*)&z[(row0 + r) * HID + c];
        *(float4*)&As[r * 132 + c] = v;
    }
    const int tr = tid >> 4, tc4 = (tid & 15) * 4;
    float acc[4][8];
#pragma unroll
    for (int i = 0; i < 4; ++i)
#pragma unroll
        for (int j = 0; j < 8; ++j) acc[i][j] = 0.f;

    for (int kc = 0; kc < 4; ++kc) {
        __syncthreads();
#pragma unroll
        for (int i = 0; i < 4; ++i) {
            int idx = i * 1024 + tid * 4;
            int r = idx >> 7, c = idx & 127;
            *(float4*)&Bs[r * 132 + c] = *(const float4*)&W1[(kc * 32 + r) * HID + c];
        }
        __syncthreads();
        micro32<132>(As, Bs, tr, tc4, kc * 32, acc);
    }
    {
        const float4 bb0 = *(const float4*)&b1[tc4];
        const float4 bb1 = *(const float4*)&b1[64 + tc4];
        __syncthreads();
#pragma unroll
        for (int i = 0; i < 4; ++i) {
            int rl = tr + 16 * i;
            float4 o0 = make_float4(fmaxf(acc[i][0] + bb0.x, 0.f), fmaxf(acc[i][1] + bb0.y, 0.f),
                                    fmaxf(acc[i][2] + bb0.z, 0.f), fmaxf(acc[i][3] + bb0.w, 0.f));
            float4 o1 = make_float4(fmaxf(acc[i][4] + bb1.x, 0.f), fmaxf(acc[i][5] + bb1.y, 0.f),
                                    fmaxf(acc[i][6] + bb1.z, 0.f), fmaxf(acc[i][7] + bb1.w, 0.f));
            *(float4*)&As[rl * 132 + tc4] = o0;
            *(float4*)&As[rl * 132 + 64 + tc4] = o1;
        }
#pragma unroll
        for (int i = 0; i < 4; ++i)
#pragma unroll
            for (int j = 0; j < 8; ++j) acc[i][j] = 0.f;
    }
    for (int kc = 0; kc < 4; ++kc) {
        __syncthreads();
#pragma unroll
        for (int i = 0; i < 4; ++i) {
            int idx = i * 1024 + tid * 4;
            int r = idx >> 7, c = idx & 127;
            *(float4*)&Bs[r * 132 + c] = *(const float4*)&W2[(kc * 32 + r) * HID + c];
        }
        __syncthreads();
        micro32<132>(As, Bs, tr, tc4, kc * 32, acc);
    }
    const float4 bb0 = *(const float4*)&b2[tc4];
    const float4 bb1 = *(const float4*)&b2[64 + tc4];
    float outv[4][8];
    bool valid[4];
#pragma unroll
    for (int i = 0; i < 4; ++i) {
        valid[i] = (row0 + tr + 16 * i) < N_NODES;
        outv[i][0] = acc[i][0] + bb0.x; outv[i][1] = acc[i][1] + bb0.y;
        outv[i][2] = acc[i][2] + bb0.z; outv[i][3] = acc[i][3] + bb0.w;
        outv[i][4] = acc[i][4] + bb1.x; outv[i][5] = acc[i][5] + bb1.y;
        outv[i][6] = acc[i][6] + bb1.z; outv[i][7] = acc[i][7] + bb1.w;
        if (valid[i]) {
            int r = row0 + tr + 16 * i;
            *(float4*)&z2[r * HID + tc4] = make_float4(outv[i][0], outv[i][1], outv[i][2], outv[i][3]);
            *(float4*)&z2[r * HID + 64 + tc4] = make_float4(outv[i][4], outv[i][5], outv[i][6], outv[i][7]);
        }
    }
    float s[8], sq[8];
#pragma unroll
    for (int j = 0; j < 8; ++j) { s[j] = 0.f; sq[j] = 0.f; }
#pragma unroll
    for (int i = 0; i < 4; ++i) {
        if (valid[i]) {
#pragma unroll
            for (int j = 0; j < 8; ++j) {
                s[j] += outv[i][j];
                sq[j] = fmaf(outv[i][j], outv[i][j], sq[j]);
            }
        }
    }
    __syncthreads();
    *(float4*)&red[tr * 128 + tc4] = make_float4(s[0], s[1], s[2], s[3]);
    *(float4*)&red[tr * 128 + 64 + tc4] = make_float4(s[4], s[5], s[6], s[7]);
    __syncthreads();
    if (tid < 128) {
        float t = 0.f;
#pragma unroll
        for (int r = 0; r < 16; ++r) t += red[r * 128 + tid];
        atomicAdd(&bn[tid], t);
    }
    __syncthreads();
    *(float4*)&red[tr * 128 + tc4] = make_float4(sq[0], sq[1], sq[2], sq[3]);
    *(float4*)&red[tr * 128 + 64 + tc4] = make_float4(sq[4], sq[5], sq[6], sq[7]);
    __syncthreads();
    if (tid < 128) {
        float t = 0.f;
#pragma unroll
        for (int r = 0; r < 16; ++r) t += red[r * 128 + tid];
        atomicAdd(&bn[128 + tid], t);
    }
}

// ---------------------------------------------------------------------------
// BN (batch stats) + ReLU -> bf16 h:  hb = bf16(relu(gamma*(z2-m)*rsqrt(v)+beta))
// ---------------------------------------------------------------------------
__global__ __launch_bounds__(256) void k_bnrelu(const float* __restrict__ z2,
                                                const float* __restrict__ bn,
                                                const float* __restrict__ gamma,
                                                const float* __restrict__ beta,
                                                unsigned short* __restrict__ hb) {
    const int idx = (blockIdx.x * 256 + threadIdx.x) * 4;   // exact: 6250*256*4 = 6.4M
    const int c = idx & 127;
    const float invN = 1.0f / (float)N_NODES;
    float4 v = *(const float4*)&z2[idx];
    float o[4] = {v.x, v.y, v.z, v.w};
#pragma unroll
    for (int k = 0; k < 4; ++k) {
        const float m = bn[c + k] * invN;
        float var = bn[128 + c + k] * invN - m * m;
        var = fmaxf(var, 0.f);
        const float r = rsqrtf(var + BN_EPS);
        o[k] = fmaxf(gamma[c + k] * (o[k] - m) * r + beta[c + k], 0.f);
    }
    *(uint2*)&hb[idx] = make_uint2(pack2(o[0], o[1]), pack2(o[2], o[3]));
}

// ---------------------------------------------------------------------------
// Global add pool (batch is sorted): register accumulate, flush on change.
// ---------------------------------------------------------------------------
__global__ void k_pool(const unsigned short* __restrict__ hb, const int* __restrict__ batch,
                       float* __restrict__ g) {
    const int f = threadIdx.x;            // 128 threads
    const int n0 = blockIdx.x * 128;
    const int nend = min(n0 + 128, N_NODES);
    float acc = 0.f;
    int cur = batch[n0];
    for (int n = n0; n < nend; ++n) {
        const int bb = batch[n];
        if (bb != cur) {
            atomicAdd(&g[cur * HID + f], acc);
            acc = 0.f;
            cur = bb;
        }
        acc += bfl((unsigned int)hb[n * HID + f]);
    }
    atomicAdd(&g[cur * HID + f], acc);
}

// ---------------------------------------------------------------------------
// Head
// ---------------------------------------------------------------------------
__global__ void k_head1(const float* __restrict__ g, const float* __restrict__ W,
                        const float* __restrict__ b, float* __restrict__ g1) {
    const int idx = blockIdx.x * 256 + threadIdx.x;   // 32*256 = 8192
    const int r = idx >> 7, c = idx & 127;
    float acc = b[c];
    for (int k = 0; k < 128; ++k) acc = fmaf(g[r * HID + k], W[k * HID + c], acc);
    g1[idx] = fmaxf(acc, 0.f);
}

__global__ void k_head2(const float* __restrict__ g1, const float* __restrict__ W,
                        const float* __restrict__ b, float* __restrict__ out) {
    const int idx = threadIdx.x;          // 128
    const int r = idx >> 1, c = idx & 1;
    float acc = b[c];
    for (int k = 0; k < 128; ++k) acc = fmaf(g1[r * HID + k], W[k * 2 + c], acc);
    out[idx] = acc;
}

// ---------------------------------------------------------------------------
// Launch
// ---------------------------------------------------------------------------
extern "C" void kernel_launch(void* const* d_in, const int* in_sizes, int n_in,
                              void* d_out, int out_size, void* d_ws, size_t ws_size,
                              hipStream_t stream) {
    const float* x     = (const float*)d_in[0];
    const int*   ei    = (const int*)d_in[1];
    const float* eattr = (const float*)d_in[2];
    const int*   batch = (const int*)d_in[3];
    const float* encW  = (const float*)d_in[4];
    const float* encb  = (const float*)d_in[5];
    const float* eW    = (const float*)d_in[6];
    const float* eb    = (const float*)d_in[7];
    const float* W1    = (const float*)d_in[8];
    const float* b1    = (const float*)d_in[9];
    const float* W2    = (const float*)d_in[10];
    const float* b2    = (const float*)d_in[11];
    const float* gam   = (const float*)d_in[12];
    const float* bet   = (const float*)d_in[13];
    const float* hW1   = (const float*)d_in[14];
    const float* hb1   = (const float*)d_in[15];
    const float* hW2   = (const float*)d_in[16];
    const float* hb2   = (const float*)d_in[17];
    float* out = (float*)d_out;

    // workspace layout (float-sized slots); total ~111 MB
    float* ws = (float*)d_ws;
    float* z   = ws;                       // 6,400,000
    float* z2  = ws + 6400000;             // 6,400,000
    float* bn  = ws + 12800000;            // 256
    float* g   = ws + 12800256;            // 8,192
    float* g1  = ws + 12808448;            // 8,192
    unsigned short* hb = (unsigned short*)(ws + 12816640);   // 6.4M bf16
    int* row_ptr = (int*)(ws + 16016640);  // 50,001
    int* cursor  = row_ptr + N_NODES + 1;  // 50,000
    int* elist   = cursor + N_NODES;       // 640,000
    int* bsums   = elist + N_EDGES;        // 256
    int* src_s   = (int*)(ws + 16756900);  // 640,000
    float* eattr_s = ws + 17396900;        // 10,240,000 (16B-aligned)

    const int* esrc = ei;
    const int* edst = ei + N_EDGES;

    // CSR build (every call; edge_index is restored before each timed call)
    hipMemsetAsync(row_ptr, 0, (N_NODES + 1) * sizeof(int), stream);
    k_hist<<<N_EDGES / 256, 256, 0, stream>>>(edst, row_ptr);
    k_blockred<<<196, 256, 0, stream>>>(row_ptr, bsums);
    k_scan_bsums<<<1, 64, 0, stream>>>(bsums, 196);
    k_scan_blocks<<<196, 256, 0, stream>>>(row_ptr, bsums, cursor);
    k_fill<<<N_EDGES / 256, 256, 0, stream>>>(edst, cursor, elist);
    k_gather<<<N_EDGES / 256, 256, 0, stream>>>(elist, esrc, eattr, src_s, eattr_s);

    // encoder -> bf16 h
    k_enc<<<782, 256, 0, stream>>>(x, encW, encb, hb);

    for (int l = 0; l < N_LAYERS; ++l) {
        k_agg<<<12500, 256, 0, stream>>>((const unsigned int*)hb, src_s, eattr_s,
                                         eW + l * EDGE_DIM * HID, eb + l * HID,
                                         row_ptr, z);
        hipMemsetAsync(bn, 0, 256 * sizeof(float), stream);
        k_mlp<<<782, 256, 0, stream>>>(z, W1 + l * HID * HID, b1 + l * HID,
                                       W2 + l * HID * HID, b2 + l * HID, z2, bn);
        k_bnrelu<<<6250, 256, 0, stream>>>(z2, bn, gam + l * HID, bet + l * HID, hb);
    }

    hipMemsetAsync(g, 0, NUM_GRAPHS * HID * sizeof(float), stream);
    k_pool<<<391, 128, 0, stream>>>(hb, batch, g);
    k_head1<<<32, 256, 0, stream>>>(g, hW1, hb1, g1);
    k_head2<<<1, 128, 0, stream>>>(g1, hW2, hb2, out);
}

// Round 5
// 647.180 us; speedup vs baseline: 1.6671x; 1.3117x over previous
//
#include <hip/hip_runtime.h>
#include <hip/hip_bf16.h>

// Problem constants (from reference)
#define N_NODES 50000
#define N_EDGES 640000
#define F_IN 64
#define EDGE_DIM 16
#define HID 128
#define N_LAYERS 3
#define NUM_GRAPHS 64
#define BN_EPS 1e-5f

typedef __attribute__((ext_vector_type(8))) short short8;   // 8 bf16 (4 VGPRs)
typedef __attribute__((ext_vector_type(4))) float f32x4;    // MFMA acc

// bf16 <-> f32 helpers (manual, RNE on pack)
__device__ __forceinline__ float bfl(unsigned int u) {
    unsigned int v = u << 16; float f; __builtin_memcpy(&f, &v, 4); return f;
}
__device__ __forceinline__ float bfh(unsigned int u) {
    unsigned int v = u & 0xffff0000u; float f; __builtin_memcpy(&f, &v, 4); return f;
}
__device__ __forceinline__ unsigned int f2bf(float f) {
    unsigned int v; __builtin_memcpy(&v, &f, 4);
    v += 0x7fffu + ((v >> 16) & 1u);
    return v >> 16;
}
__device__ __forceinline__ unsigned int pack2(float lo, float hi) {
    return f2bf(lo) | (f2bf(hi) << 16);
}

// ---------------------------------------------------------------------------
// CSR build: histogram -> block reduce -> scan of block sums -> block scan ->
// bucket fill. row_ptr doubles as the degree array during the histogram.
// ---------------------------------------------------------------------------
__global__ void k_hist(const int* __restrict__ dst, int* __restrict__ deg) {
    int e = blockIdx.x * 256 + threadIdx.x;   // grid exact: 2500*256 = 640000
    atomicAdd(&deg[dst[e]], 1);
}

__global__ void k_blockred(const int* __restrict__ deg, int* __restrict__ bsums) {
    __shared__ int s[256];
    int i = blockIdx.x * 256 + threadIdx.x;
    int v = (i < N_NODES) ? deg[i] : 0;
    s[threadIdx.x] = v;
    __syncthreads();
    for (int off = 128; off > 0; off >>= 1) {
        if (threadIdx.x < off) s[threadIdx.x] += s[threadIdx.x + off];
        __syncthreads();
    }
    if (threadIdx.x == 0) bsums[blockIdx.x] = s[0];
}

__global__ void k_scan_bsums(int* __restrict__ bsums, int nb) {
    if (threadIdx.x == 0) {
        int run = 0;
        for (int i = 0; i < nb; ++i) { int v = bsums[i]; bsums[i] = run; run += v; }
    }
}

__global__ void k_scan_blocks(int* __restrict__ deg_rowptr, const int* __restrict__ bsums,
                              int* __restrict__ cursor) {
    __shared__ int s[256];
    int tid = threadIdx.x;
    int i = blockIdx.x * 256 + tid;
    int v = (i < N_NODES) ? deg_rowptr[i] : 0;
    s[tid] = v;
    __syncthreads();
    for (int off = 1; off < 256; off <<= 1) {
        int t = 0;
        if (tid >= off) t = s[tid - off];
        __syncthreads();
        s[tid] += t;
        __syncthreads();
    }
    int excl = s[tid] - v + bsums[blockIdx.x];
    if (i < N_NODES) {
        deg_rowptr[i] = excl;
        cursor[i] = excl;
    }
    if (i == N_NODES - 1) deg_rowptr[N_NODES] = N_EDGES;
}

__global__ void k_fill(const int* __restrict__ dst, int* __restrict__ cursor,
                       int* __restrict__ elist) {
    int e = blockIdx.x * 256 + threadIdx.x;   // exact
    int p = atomicAdd(&cursor[dst[e]], 1);
    elist[p] = e;
}

// ---------------------------------------------------------------------------
// Edge materialization in CSR order: src_s[p] = esrc[elist[p]],
// eattr_s[p*16..] = eattr[elist[p]*16..].
// ---------------------------------------------------------------------------
__global__ void k_gather(const int* __restrict__ elist, const int* __restrict__ esrc,
                         const float* __restrict__ eattr,
                         int* __restrict__ src_s, float* __restrict__ eattr_s) {
    const int p = blockIdx.x * 256 + threadIdx.x;   // exact: 2500*256
    const int eid = elist[p];
    src_s[p] = esrc[eid];
    const float4 a0 = *(const float4*)&eattr[eid * EDGE_DIM];
    const float4 a1 = *(const float4*)&eattr[eid * EDGE_DIM + 4];
    const float4 a2 = *(const float4*)&eattr[eid * EDGE_DIM + 8];
    const float4 a3 = *(const float4*)&eattr[eid * EDGE_DIM + 12];
    *(float4*)&eattr_s[p * EDGE_DIM] = a0;
    *(float4*)&eattr_s[p * EDGE_DIM + 4] = a1;
    *(float4*)&eattr_s[p * EDGE_DIM + 8] = a2;
    *(float4*)&eattr_s[p * EDGE_DIM + 12] = a3;
}

// ---------------------------------------------------------------------------
// Weight pack for MFMA B-fragments: for each of 6 matrices (3x W1, 3x W2),
// wp[mat][kstep][ntile][lane][j] = bf16(W[kstep*32 + (lane>>4)*8 + j][ntile*16 + (lane&15)])
// B-frag load in GEMM = one coalesced 16B load per lane.
// ---------------------------------------------------------------------------
__global__ void k_packW(const float* __restrict__ W1, const float* __restrict__ W2,
                        unsigned short* __restrict__ wp) {
    const int t = blockIdx.x * 256 + threadIdx.x;   // 48*256 = 12288 exact
    const int mat = t >> 11;            // 0..5
    const int r = t & 2047;
    const int kstep = r >> 9;           // 0..3
    const int ntile = (r >> 6) & 7;     // 0..7
    const int lane = r & 63;
    const float* W = (mat < 3) ? (W1 + mat * 16384) : (W2 + (mat - 3) * 16384);
    const int kbase = kstep * 32 + ((lane >> 4) << 3);
    const int n = ntile * 16 + (lane & 15);
    unsigned int o[4];
#pragma unroll
    for (int jj = 0; jj < 4; ++jj)
        o[jj] = pack2(W[(kbase + 2 * jj) * HID + n], W[(kbase + 2 * jj + 1) * HID + n]);
    uint4* dst = (uint4*)(wp + (size_t)mat * 16384 + (((kstep << 3) + ntile) * 64 + lane) * 8);
    *dst = make_uint4(o[0], o[1], o[2], o[3]);
}

// ---------------------------------------------------------------------------
// fp32 GEMM micro-kernel (encoder only): 64x128 tile, 256 threads.
// ---------------------------------------------------------------------------
template <int LDA>
__device__ __forceinline__ void micro32(const float* __restrict__ As,
                                        const float* __restrict__ Bs,
                                        int tr, int tc4, int koff,
                                        float acc[4][8]) {
#pragma unroll
    for (int k4 = 0; k4 < 32; k4 += 4) {
        float4 a4[4];
#pragma unroll
        for (int i = 0; i < 4; ++i)
            a4[i] = *(const float4*)&As[(tr + 16 * i) * LDA + koff + k4];
#pragma unroll
        for (int kk = 0; kk < 4; ++kk) {
            const float4 b0v = *(const float4*)&Bs[(k4 + kk) * 132 + tc4];
            const float4 b1v = *(const float4*)&Bs[(k4 + kk) * 132 + 64 + tc4];
#pragma unroll
            for (int i = 0; i < 4; ++i) {
                const float av = ((const float*)&a4[i])[kk];
                acc[i][0] = fmaf(av, b0v.x, acc[i][0]);
                acc[i][1] = fmaf(av, b0v.y, acc[i][1]);
                acc[i][2] = fmaf(av, b0v.z, acc[i][2]);
                acc[i][3] = fmaf(av, b0v.w, acc[i][3]);
                acc[i][4] = fmaf(av, b1v.x, acc[i][4]);
                acc[i][5] = fmaf(av, b1v.y, acc[i][5]);
                acc[i][6] = fmaf(av, b1v.z, acc[i][6]);
                acc[i][7] = fmaf(av, b1v.w, acc[i][7]);
            }
        }
    }
}

// ---------------------------------------------------------------------------
// Encoder: hb = bf16(x @ enc_W + enc_b)   (M=50000, K=64, N=128)
// ---------------------------------------------------------------------------
__global__ __launch_bounds__(256) void k_enc(const float* __restrict__ x,
                                             const float* __restrict__ W,
                                             const float* __restrict__ b,
                                             unsigned short* __restrict__ hb) {
    __shared__ float As[64 * 68];
    __shared__ float Bs[32 * 132];
    const int tid = threadIdx.x;
    const int row0 = blockIdx.x * 64;
#pragma unroll
    for (int i = 0; i < 4; ++i) {
        int idx = i * 1024 + tid * 4;
        int r = idx >> 6, c = idx & 63;
        float4 v = make_float4(0.f, 0.f, 0.f, 0.f);
        if (row0 + r < N_NODES) v = *(const float4*)&x[(row0 + r) * F_IN + c];
        *(float4*)&As[r * 68 + c] = v;
    }
    float acc[4][8];
#pragma unroll
    for (int i = 0; i < 4; ++i)
#pragma unroll
        for (int j = 0; j < 8; ++j) acc[i][j] = 0.f;

    const int tr = tid >> 4, tc4 = (tid & 15) * 4;
    for (int kc = 0; kc < 2; ++kc) {
        __syncthreads();
#pragma unroll
        for (int i = 0; i < 4; ++i) {
            int idx = i * 1024 + tid * 4;
            int r = idx >> 7, c = idx & 127;
            *(float4*)&Bs[r * 132 + c] = *(const float4*)&W[(kc * 32 + r) * HID + c];
        }
        __syncthreads();
        micro32<68>(As, Bs, tr, tc4, kc * 32, acc);
    }
    const float4 bb0 = *(const float4*)&b[tc4];
    const float4 bb1 = *(const float4*)&b[64 + tc4];
#pragma unroll
    for (int i = 0; i < 4; ++i) {
        int r = row0 + tr + 16 * i;
        if (r < N_NODES) {
            unsigned int p0 = pack2(acc[i][0] + bb0.x, acc[i][1] + bb0.y);
            unsigned int p1 = pack2(acc[i][2] + bb0.z, acc[i][3] + bb0.w);
            unsigned int p2 = pack2(acc[i][4] + bb1.x, acc[i][5] + bb1.y);
            unsigned int p3 = pack2(acc[i][6] + bb1.z, acc[i][7] + bb1.w);
            *(uint2*)&hb[r * HID + tc4] = make_uint2(p0, p1);
            *(uint2*)&hb[r * HID + 64 + tc4] = make_uint2(p2, p3);
        }
    }
}

// ---------------------------------------------------------------------------
// GINE aggregation (unchanged structure from round 4, now writes bf16 z):
// z[n] = h[n] + sum_{p in CSR[n]} relu(h[src_s[p]] + eattr_s[p] @ We + be)
// ---------------------------------------------------------------------------
#define EFMA2(AV, J)                                  \
    ef.x = fmaf((AV), w[J].x, ef.x);                  \
    ef.y = fmaf((AV), w[J].y, ef.y);

__global__ __launch_bounds__(256, 2) void k_agg(const unsigned int* __restrict__ hb32,
                                                const int* __restrict__ src_s,
                                                const float* __restrict__ eattr_s,
                                                const float* __restrict__ We,
                                                const float* __restrict__ be,
                                                const int* __restrict__ row_ptr,
                                                unsigned int* __restrict__ zb32) {
    const int lane = threadIdx.x & 63;
    const int wv = threadIdx.x >> 6;          // wave in block (0..3)
    const int f2 = lane * 2;
    float2 w[16];
#pragma unroll
    for (int j = 0; j < 16; ++j) w[j] = *(const float2*)&We[j * HID + f2];
    const float2 eb = *(const float2*)&be[f2];

    const int n = blockIdx.x * 4 + wv;        // grid exact: 12500*4 = 50000
    const int base = __builtin_amdgcn_readfirstlane(row_ptr[n]);
    const int deg = __builtin_amdgcn_readfirstlane(row_ptr[n + 1]) - base;

    const unsigned int hself = hb32[n * 64 + lane];
    float2 acc = make_float2(bfl(hself), bfh(hself));

    if (deg > 0) {
        const int* sp = src_s + base;                        // uniform, sequential
        const float* ep = eattr_s + (size_t)base * EDGE_DIM; // uniform, sequential
        const int last = deg - 1;
        const int nch = (deg + 7) >> 3;

        int srcN[8];
        unsigned int huC[8];
        {
            int s0[8];
#pragma unroll
            for (int j = 0; j < 8; ++j) s0[j] = sp[min(j, last)];
#pragma unroll
            for (int j = 0; j < 8; ++j) huC[j] = hb32[s0[j] * 64 + lane];
        }
#pragma unroll
        for (int j = 0; j < 8; ++j) srcN[j] = sp[min(8 + j, last)];

        for (int c = 0; c < nch; ++c) {
            const bool more = (c + 1) < nch;
            unsigned int huN[8];
            if (more) {
#pragma unroll
                for (int j = 0; j < 8; ++j) huN[j] = hb32[srcN[j] * 64 + lane];
            }
            int srcNN[8];
            if (c + 2 < nch) {
#pragma unroll
                for (int j = 0; j < 8; ++j) srcNN[j] = sp[min((c + 2) * 8 + j, last)];
            }
            const int rem = deg - c * 8;
            const float* epc = ep + (size_t)(c * 8) * EDGE_DIM;
#pragma unroll
            for (int j = 0; j < 8; ++j) {
                if (j < rem) {
                    const float4 a0 = *(const float4*)&epc[j * EDGE_DIM];
                    const float4 a1 = *(const float4*)&epc[j * EDGE_DIM + 4];
                    const float4 a2 = *(const float4*)&epc[j * EDGE_DIM + 8];
                    const float4 a3 = *(const float4*)&epc[j * EDGE_DIM + 12];
                    float2 ef = eb;
                    EFMA2(a0.x, 0)  EFMA2(a0.y, 1)  EFMA2(a0.z, 2)  EFMA2(a0.w, 3)
                    EFMA2(a1.x, 4)  EFMA2(a1.y, 5)  EFMA2(a1.z, 6)  EFMA2(a1.w, 7)
                    EFMA2(a2.x, 8)  EFMA2(a2.y, 9)  EFMA2(a2.z, 10) EFMA2(a2.w, 11)
                    EFMA2(a3.x, 12) EFMA2(a3.y, 13) EFMA2(a3.z, 14) EFMA2(a3.w, 15)
                    acc.x += fmaxf(bfl(huC[j]) + ef.x, 0.f);
                    acc.y += fmaxf(bfh(huC[j]) + ef.y, 0.f);
                }
            }
            if (more) {
#pragma unroll
                for (int j = 0; j < 8; ++j) { huC[j] = huN[j]; srcN[j] = srcNN[j]; }
            }
        }
    }
    zb32[n * 64 + lane] = pack2(acc.x, acc.y);
}

// ---------------------------------------------------------------------------
// Fused node MLP via bf16 MFMA (16x16x32):
//   z2 = relu(z @ W1 + b1) @ W2 + b2  (+ BN sum/sumsq partials)
// Block = 4 waves x 16 rows = 64 rows. Per wave: 8 col-tiles x 4 K-steps x
// 2 GEMMs = 64 MFMAs. z1 round-trips through a wave-private LDS slab
// (C-layout -> A-layout transform). Verified layouts (m89/m120):
//   A[m=lane&15][k=(lane>>4)*8+j]; B[k=(lane>>4)*8+j][n=lane&15];
//   C/D row=(lane>>4)*4+reg, col=lane&15.
// ---------------------------------------------------------------------------
#define Z1LD 136   // bf16 elements per row: 272B, 16B-aligned, +8 pad for banks

__global__ __launch_bounds__(256, 3) void k_mlp(const unsigned short* __restrict__ zb,
                                                const unsigned short* __restrict__ w1p,
                                                const float* __restrict__ b1,
                                                const unsigned short* __restrict__ w2p,
                                                const float* __restrict__ b2,
                                                float* __restrict__ z2,
                                                float* __restrict__ bn) {
    __shared__ unsigned short z1s[64 * Z1LD];
    __shared__ float redA[512];
    __shared__ float redB[512];
    const int tid = threadIdx.x;
    const int w = tid >> 6, lane = tid & 63;
    const int q = lane >> 4, l15 = lane & 15;
    const int row0 = blockIdx.x * 64 + w * 16;          // wave's row slab

    // ---- GEMM1: z @ W1 ----
    const int ar = min(row0 + l15, N_NODES - 1);
    const unsigned short* aptr = zb + (size_t)ar * HID + q * 8;

    f32x4 acc[8];
#pragma unroll
    for (int nt = 0; nt < 8; ++nt) acc[nt] = (f32x4){0.f, 0.f, 0.f, 0.f};

#pragma unroll
    for (int ks = 0; ks < 4; ++ks) {
        const short8 a = *(const short8*)(aptr + ks * 32);
#pragma unroll
        for (int nt = 0; nt < 8; ++nt) {
            const short8 b = *(const short8*)(w1p + (((ks << 3) + nt) * 64 + lane) * 8);
            acc[nt] = __builtin_amdgcn_mfma_f32_16x16x32_bf16(a, b, acc[nt], 0, 0, 0);
        }
    }
    // bias + relu -> z1 (bf16) into wave-private LDS rows
    {
        const int lr0 = w * 16 + q * 4;
#pragma unroll
        for (int nt = 0; nt < 8; ++nt) {
            const float bias = b1[nt * 16 + l15];
            const int cc = nt * 16 + l15;
#pragma unroll
            for (int reg = 0; reg < 4; ++reg) {
                const float v = fmaxf(acc[nt][reg] + bias, 0.f);
                z1s[(lr0 + reg) * Z1LD + cc] = (unsigned short)f2bf(v);
            }
        }
    }
    // ---- GEMM2: z1 @ W2 ----
#pragma unroll
    for (int nt = 0; nt < 8; ++nt) acc[nt] = (f32x4){0.f, 0.f, 0.f, 0.f};
    const unsigned short* a2p = &z1s[(w * 16 + l15) * Z1LD + q * 8];
#pragma unroll
    for (int ks = 0; ks < 4; ++ks) {
        const short8 a = *(const short8*)(a2p + ks * 32);
#pragma unroll
        for (int nt = 0; nt < 8; ++nt) {
            const short8 b = *(const short8*)(w2p + (((ks << 3) + nt) * 64 + lane) * 8);
            acc[nt] = __builtin_amdgcn_mfma_f32_16x16x32_bf16(a, b, acc[nt], 0, 0, 0);
        }
    }
    // ---- epilogue: bias, z2 store (fp32), BN partials ----
    float s[8], sq[8];
    const int rowb = row0 + q * 4;
#pragma unroll
    for (int nt = 0; nt < 8; ++nt) {
        const float bias = b2[nt * 16 + l15];
        const int cc = nt * 16 + l15;
        float ls = 0.f, lq = 0.f;
#pragma unroll
        for (int reg = 0; reg < 4; ++reg) {
            const int r = rowb + reg;
            const float v = acc[nt][reg] + bias;
            if (r < N_NODES) {
                z2[(size_t)r * HID + cc] = v;
                ls += v;
                lq = fmaf(v, v, lq);
            }
        }
        s[nt] = ls; sq[nt] = lq;
    }
    // reduce across the 4 quads (lanes sharing l15 hold the same columns)
#pragma unroll
    for (int nt = 0; nt < 8; ++nt) {
        s[nt] += __shfl_xor(s[nt], 16, 64);
        s[nt] += __shfl_xor(s[nt], 32, 64);
        sq[nt] += __shfl_xor(sq[nt], 16, 64);
        sq[nt] += __shfl_xor(sq[nt], 32, 64);
    }
    if (lane < 16) {
#pragma unroll
        for (int nt = 0; nt < 8; ++nt) {
            redA[w * 128 + nt * 16 + lane] = s[nt];
            redB[w * 128 + nt * 16 + lane] = sq[nt];
        }
    }
    __syncthreads();
    if (tid < 128) {
        float t = redA[tid] + redA[128 + tid] + redA[256 + tid] + redA[384 + tid];
        atomicAdd(&bn[tid], t);
    } else {
        const int c = tid - 128;
        float t = redB[c] + redB[128 + c] + redB[256 + c] + redB[384 + c];
        atomicAdd(&bn[128 + c], t);
    }
}

// ---------------------------------------------------------------------------
// BN (batch stats) + ReLU -> bf16 h
// ---------------------------------------------------------------------------
__global__ __launch_bounds__(256) void k_bnrelu(const float* __restrict__ z2,
                                                const float* __restrict__ bn,
                                                const float* __restrict__ gamma,
                                                const float* __restrict__ beta,
                                                unsigned short* __restrict__ hb) {
    const int idx = (blockIdx.x * 256 + threadIdx.x) * 4;   // exact: 6250*256*4 = 6.4M
    const int c = idx & 127;
    const float invN = 1.0f / (float)N_NODES;
    float4 v = *(const float4*)&z2[idx];
    float o[4] = {v.x, v.y, v.z, v.w};
#pragma unroll
    for (int k = 0; k < 4; ++k) {
        const float m = bn[c + k] * invN;
        float var = bn[128 + c + k] * invN - m * m;
        var = fmaxf(var, 0.f);
        const float r = rsqrtf(var + BN_EPS);
        o[k] = fmaxf(gamma[c + k] * (o[k] - m) * r + beta[c + k], 0.f);
    }
    *(uint2*)&hb[idx] = make_uint2(pack2(o[0], o[1]), pack2(o[2], o[3]));
}

// ---------------------------------------------------------------------------
// Global add pool (batch is sorted): register accumulate, flush on change.
// ---------------------------------------------------------------------------
__global__ void k_pool(const unsigned short* __restrict__ hb, const int* __restrict__ batch,
                       float* __restrict__ g) {
    const int f = threadIdx.x;            // 128 threads
    const int n0 = blockIdx.x * 128;
    const int nend = min(n0 + 128, N_NODES);
    float acc = 0.f;
    int cur = batch[n0];
    for (int n = n0; n < nend; ++n) {
        const int bb = batch[n];
        if (bb != cur) {
            atomicAdd(&g[cur * HID + f], acc);
            acc = 0.f;
            cur = bb;
        }
        acc += bfl((unsigned int)hb[n * HID + f]);
    }
    atomicAdd(&g[cur * HID + f], acc);
}

// ---------------------------------------------------------------------------
// Head
// ---------------------------------------------------------------------------
__global__ void k_head1(const float* __restrict__ g, const float* __restrict__ W,
                        const float* __restrict__ b, float* __restrict__ g1) {
    const int idx = blockIdx.x * 256 + threadIdx.x;   // 32*256 = 8192
    const int r = idx >> 7, c = idx & 127;
    float acc = b[c];
    for (int k = 0; k < 128; ++k) acc = fmaf(g[r * HID + k], W[k * HID + c], acc);
    g1[idx] = fmaxf(acc, 0.f);
}

__global__ void k_head2(const float* __restrict__ g1, const float* __restrict__ W,
                        const float* __restrict__ b, float* __restrict__ out) {
    const int idx = threadIdx.x;          // 128
    const int r = idx >> 1, c = idx & 1;
    float acc = b[c];
    for (int k = 0; k < 128; ++k) acc = fmaf(g1[r * HID + k], W[k * 2 + c], acc);
    out[idx] = acc;
}

// ---------------------------------------------------------------------------
// Launch
// ---------------------------------------------------------------------------
extern "C" void kernel_launch(void* const* d_in, const int* in_sizes, int n_in,
                              void* d_out, int out_size, void* d_ws, size_t ws_size,
                              hipStream_t stream) {
    const float* x     = (const float*)d_in[0];
    const int*   ei    = (const int*)d_in[1];
    const float* eattr = (const float*)d_in[2];
    const int*   batch = (const int*)d_in[3];
    const float* encW  = (const float*)d_in[4];
    const float* encb  = (const float*)d_in[5];
    const float* eW    = (const float*)d_in[6];
    const float* eb    = (const float*)d_in[7];
    const float* W1    = (const float*)d_in[8];
    const float* b1    = (const float*)d_in[9];
    const float* W2    = (const float*)d_in[10];
    const float* b2    = (const float*)d_in[11];
    const float* gam   = (const float*)d_in[12];
    const float* bet   = (const float*)d_in[13];
    const float* hW1   = (const float*)d_in[14];
    const float* hb1   = (const float*)d_in[15];
    const float* hW2   = (const float*)d_in[16];
    const float* hb2   = (const float*)d_in[17];
    float* out = (float*)d_out;

    // workspace layout (float-sized slots); total ~98 MB
    float* ws = (float*)d_ws;
    float* z2  = ws;                        // 6,400,000
    float* bn  = ws + 6400000;              // 256
    float* g   = ws + 6400256;              // 8,192
    float* g1  = ws + 6408448;              // 8,192
    unsigned short* hb = (unsigned short*)(ws + 6416640);   // 6.4M bf16 (3.2M floats)
    unsigned int* zb32 = (unsigned int*)(ws + 9616640);     // 6.4M bf16 (3.2M floats)
    int* row_ptr = (int*)(ws + 12816640);   // 50,001
    int* cursor  = row_ptr + N_NODES + 1;   // 50,000
    int* elist   = cursor + N_NODES;        // 640,000
    int* bsums   = elist + N_EDGES;         // 256
    int* src_s   = bsums + 256;             // 640,000
    float* eattr_s = ws + 14196900;         // 10,240,000 (16B aligned)
    unsigned short* wp = (unsigned short*)(ws + 24436900);  // 98,304 bf16 packed weights

    const int* esrc = ei;
    const int* edst = ei + N_EDGES;

    // CSR build + edge materialization (per call)
    hipMemsetAsync(row_ptr, 0, (N_NODES + 1) * sizeof(int), stream);
    k_hist<<<N_EDGES / 256, 256, 0, stream>>>(edst, row_ptr);
    k_blockred<<<196, 256, 0, stream>>>(row_ptr, bsums);
    k_scan_bsums<<<1, 64, 0, stream>>>(bsums, 196);
    k_scan_blocks<<<196, 256, 0, stream>>>(row_ptr, bsums, cursor);
    k_fill<<<N_EDGES / 256, 256, 0, stream>>>(edst, cursor, elist);
    k_gather<<<N_EDGES / 256, 256, 0, stream>>>(elist, esrc, eattr, src_s, eattr_s);

    // MFMA weight packing (3x W1, 3x W2)
    k_packW<<<48, 256, 0, stream>>>(W1, W2, wp);

    // encoder -> bf16 h
    k_enc<<<782, 256, 0, stream>>>(x, encW, encb, hb);

    for (int l = 0; l < N_LAYERS; ++l) {
        k_agg<<<12500, 256, 0, stream>>>((const unsigned int*)hb, src_s, eattr_s,
                                         eW + l * EDGE_DIM * HID, eb + l * HID,
                                         row_ptr, zb32);
        hipMemsetAsync(bn, 0, 256 * sizeof(float), stream);
        k_mlp<<<782, 256, 0, stream>>>((const unsigned short*)zb32,
                                       wp + (size_t)l * 16384, b1 + l * HID,
                                       wp + (size_t)(3 + l) * 16384, b2 + l * HID,
                                       z2, bn);
        k_bnrelu<<<6250, 256, 0, stream>>>(z2, bn, gam + l * HID, bet + l * HID, hb);
    }

    hipMemsetAsync(g, 0, NUM_GRAPHS * HID * sizeof(float), stream);
    k_pool<<<391, 128, 0, stream>>>(hb, batch, g);
    k_head1<<<32, 256, 0, stream>>>(g, hW1, hb1, g1);
    k_head2<<<1, 128, 0, stream>>>(g1, hW2, hb2, out);
}

// Round 7
// 609.314 us; speedup vs baseline: 1.7707x; 1.0621x over previous
//
#include <hip/hip_runtime.h>
#include <hip/hip_bf16.h>

// Problem constants (from reference)
#define N_NODES 50000
#define N_EDGES 640000
#define F_IN 64
#define EDGE_DIM 16
#define HID 128
#define N_LAYERS 3
#define NUM_GRAPHS 64
#define BN_EPS 1e-5f

typedef __attribute__((ext_vector_type(8))) short short8;    // 8 bf16 (4 VGPRs)
typedef __attribute__((ext_vector_type(4))) float f32x4;     // MFMA acc
typedef __attribute__((ext_vector_type(2))) __fp16 half2v;   // packed f16 pair (builtin type)

// bf16 <-> f32 helpers (manual, RNE on pack)
__device__ __forceinline__ float bfl(unsigned int u) {
    unsigned int v = u << 16; float f; __builtin_memcpy(&f, &v, 4); return f;
}
__device__ __forceinline__ float bfh(unsigned int u) {
    unsigned int v = u & 0xffff0000u; float f; __builtin_memcpy(&f, &v, 4); return f;
}
__device__ __forceinline__ unsigned int f2bf(float f) {
    unsigned int v; __builtin_memcpy(&v, &f, 4);
    v += 0x7fffu + ((v >> 16) & 1u);
    return v >> 16;
}
__device__ __forceinline__ unsigned int pack2(float lo, float hi) {
    return f2bf(lo) | (f2bf(hi) << 16);
}
__device__ __forceinline__ half2v u2h(unsigned int u) {
    half2v h; __builtin_memcpy(&h, &u, 4); return h;
}
__device__ __forceinline__ unsigned int pkh(float a, float b) {
    half2v h = __builtin_amdgcn_cvt_pkrtz(a, b);
    unsigned int u; __builtin_memcpy(&u, &h, 4); return u;
}

// ---------------------------------------------------------------------------
// CSR build: histogram -> block reduce -> scan of block sums -> block scan ->
// bucket fill. row_ptr doubles as the degree array during the histogram.
// ---------------------------------------------------------------------------
__global__ void k_hist(const int* __restrict__ dst, int* __restrict__ deg) {
    int e = blockIdx.x * 256 + threadIdx.x;   // grid exact: 2500*256 = 640000
    atomicAdd(&deg[dst[e]], 1);
}

__global__ void k_blockred(const int* __restrict__ deg, int* __restrict__ bsums) {
    __shared__ int s[256];
    int i = blockIdx.x * 256 + threadIdx.x;
    int v = (i < N_NODES) ? deg[i] : 0;
    s[threadIdx.x] = v;
    __syncthreads();
    for (int off = 128; off > 0; off >>= 1) {
        if (threadIdx.x < off) s[threadIdx.x] += s[threadIdx.x + off];
        __syncthreads();
    }
    if (threadIdx.x == 0) bsums[blockIdx.x] = s[0];
}

__global__ void k_scan_bsums(int* __restrict__ bsums, int nb) {
    if (threadIdx.x == 0) {
        int run = 0;
        for (int i = 0; i < nb; ++i) { int v = bsums[i]; bsums[i] = run; run += v; }
    }
}

__global__ void k_scan_blocks(int* __restrict__ deg_rowptr, const int* __restrict__ bsums,
                              int* __restrict__ cursor) {
    __shared__ int s[256];
    int tid = threadIdx.x;
    int i = blockIdx.x * 256 + tid;
    int v = (i < N_NODES) ? deg_rowptr[i] : 0;
    s[tid] = v;
    __syncthreads();
    for (int off = 1; off < 256; off <<= 1) {
        int t = 0;
        if (tid >= off) t = s[tid - off];
        __syncthreads();
        s[tid] += t;
        __syncthreads();
    }
    int excl = s[tid] - v + bsums[blockIdx.x];
    if (i < N_NODES) {
        deg_rowptr[i] = excl;
        cursor[i] = excl;
    }
    if (i == N_NODES - 1) deg_rowptr[N_NODES] = N_EDGES;
}

__global__ void k_fill(const int* __restrict__ dst, int* __restrict__ cursor,
                       int* __restrict__ elist) {
    int e = blockIdx.x * 256 + threadIdx.x;   // exact
    int p = atomicAdd(&cursor[dst[e]], 1);
    elist[p] = e;
}

// ---------------------------------------------------------------------------
// Edge materialization in CSR order: src_s[p] = esrc[elist[p]],
// eattr_h[p] = f16-pair packed eattr[elist[p]] (8 u32 = 32B per edge).
// ---------------------------------------------------------------------------
__global__ void k_gather(const int* __restrict__ elist, const int* __restrict__ esrc,
                         const float* __restrict__ eattr,
                         int* __restrict__ src_s, uint4* __restrict__ eattr_h) {
    const int p = blockIdx.x * 256 + threadIdx.x;   // exact: 2500*256
    const int eid = elist[p];
    src_s[p] = esrc[eid];
    const float4 a0 = *(const float4*)&eattr[eid * EDGE_DIM];
    const float4 a1 = *(const float4*)&eattr[eid * EDGE_DIM + 4];
    const float4 a2 = *(const float4*)&eattr[eid * EDGE_DIM + 8];
    const float4 a3 = *(const float4*)&eattr[eid * EDGE_DIM + 12];
    eattr_h[p * 2] = make_uint4(pkh(a0.x, a0.y), pkh(a0.z, a0.w),
                                pkh(a1.x, a1.y), pkh(a1.z, a1.w));
    eattr_h[p * 2 + 1] = make_uint4(pkh(a2.x, a2.y), pkh(a2.z, a2.w),
                                    pkh(a3.x, a3.y), pkh(a3.z, a3.w));
}

// ---------------------------------------------------------------------------
// Weight packs
// ---------------------------------------------------------------------------
// MFMA B-frag pack for 3x W1 + 3x W2 (K=128):
__global__ void k_packW(const float* __restrict__ W1, const float* __restrict__ W2,
                        unsigned short* __restrict__ wp) {
    const int t = blockIdx.x * 256 + threadIdx.x;   // 48*256 = 12288 exact
    const int mat = t >> 11;            // 0..5
    const int r = t & 2047;
    const int kstep = r >> 9;           // 0..3
    const int ntile = (r >> 6) & 7;     // 0..7
    const int lane = r & 63;
    const float* W = (mat < 3) ? (W1 + mat * 16384) : (W2 + (mat - 3) * 16384);
    const int kbase = kstep * 32 + ((lane >> 4) << 3);
    const int n = ntile * 16 + (lane & 15);
    unsigned int o[4];
#pragma unroll
    for (int jj = 0; jj < 4; ++jj)
        o[jj] = pack2(W[(kbase + 2 * jj) * HID + n], W[(kbase + 2 * jj + 1) * HID + n]);
    *(uint4*)(wp + (size_t)mat * 16384 + (((kstep << 3) + ntile) * 64 + lane) * 8) =
        make_uint4(o[0], o[1], o[2], o[3]);
}

// MFMA B-frag pack for enc_W (K=64):
__global__ void k_packEnc(const float* __restrict__ W, unsigned short* __restrict__ wpe) {
    const int t = blockIdx.x * 256 + threadIdx.x;   // 4*256 = 1024 exact
    const int kstep = t >> 9;           // 0..1
    const int ntile = (t >> 6) & 7;     // 0..7
    const int lane = t & 63;
    const int kbase = kstep * 32 + ((lane >> 4) << 3);
    const int n = ntile * 16 + (lane & 15);
    unsigned int o[4];
#pragma unroll
    for (int jj = 0; jj < 4; ++jj)
        o[jj] = pack2(W[(kbase + 2 * jj) * HID + n], W[(kbase + 2 * jj + 1) * HID + n]);
    *(uint4*)(wpe + (((kstep << 3) + ntile) * 64 + lane) * 8) =
        make_uint4(o[0], o[1], o[2], o[3]);
}

// f16-pair pack of edge weights: wek[l*1024 + kp*128 + f] = (We[2kp][f], We[2kp+1][f])
__global__ void k_packWe(const float* __restrict__ eW, unsigned int* __restrict__ wek) {
    const int t = blockIdx.x * 256 + threadIdx.x;   // 12*256 = 3072 exact
    const int l = t >> 10;
    const int r = t & 1023;
    const int kp = r >> 7, f = r & 127;
    const float a = eW[(l * EDGE_DIM + 2 * kp) * HID + f];
    const float b = eW[(l * EDGE_DIM + 2 * kp + 1) * HID + f];
    wek[t] = pkh(a, b);
}

// ---------------------------------------------------------------------------
// x -> bf16 cast (packed pairs)
// ---------------------------------------------------------------------------
__global__ void k_xcast(const float* __restrict__ x, unsigned int* __restrict__ xb32) {
    const int i = blockIdx.x * 256 + threadIdx.x;   // 6250*256 = 1.6M exact
    const float2 v = *(const float2*)&x[i * 2];
    xb32[i] = pack2(v.x, v.y);
}

// ---------------------------------------------------------------------------
// Encoder via MFMA: hb = bf16(x @ enc_W + enc_b)  (K=64, 16 MFMAs/wave)
// ---------------------------------------------------------------------------
__global__ __launch_bounds__(256, 3) void k_encm(const unsigned short* __restrict__ xb,
                                                 const unsigned short* __restrict__ wpe,
                                                 const float* __restrict__ b,
                                                 unsigned short* __restrict__ hb) {
    const int tid = threadIdx.x;
    const int w = tid >> 6, lane = tid & 63;
    const int q = lane >> 4, l15 = lane & 15;
    const int row0 = blockIdx.x * 64 + w * 16;
    const int ar = min(row0 + l15, N_NODES - 1);
    const unsigned short* aptr = xb + (size_t)ar * F_IN + q * 8;
    f32x4 acc[8];
#pragma unroll
    for (int nt = 0; nt < 8; ++nt) acc[nt] = (f32x4){0.f, 0.f, 0.f, 0.f};
#pragma unroll
    for (int ks = 0; ks < 2; ++ks) {
        const short8 a = *(const short8*)(aptr + ks * 32);
#pragma unroll
        for (int nt = 0; nt < 8; ++nt) {
            const short8 bf = *(const short8*)(wpe + (((ks << 3) + nt) * 64 + lane) * 8);
            acc[nt] = __builtin_amdgcn_mfma_f32_16x16x32_bf16(a, bf, acc[nt], 0, 0, 0);
        }
    }
    const int rowb = row0 + q * 4;
#pragma unroll
    for (int nt = 0; nt < 8; ++nt) {
        const float bias = b[nt * 16 + l15];
        const int cc = nt * 16 + l15;
#pragma unroll
        for (int reg = 0; reg < 4; ++reg) {
            const int r = rowb + reg;
            if (r < N_NODES)
                hb[(size_t)r * HID + cc] = (unsigned short)f2bf(acc[nt][reg] + bias);
        }
    }
}

// ---------------------------------------------------------------------------
// GINE aggregation v6: z[n] = h[n] + sum relu(h[src] + attr.We + be)
// One wave/node. f16 dot2 edge-MLP (16 fdot2/edge). Chunk-of-4 with
// depth-2 gather pipeline (gathers for c+2 issued at c).
// ---------------------------------------------------------------------------
__global__ __launch_bounds__(256, 2) void k_agg(const unsigned int* __restrict__ hb32,
                                                const int* __restrict__ src_s,
                                                const uint4* __restrict__ eattr_h,
                                                const unsigned int* __restrict__ wek,
                                                const float* __restrict__ be,
                                                const int* __restrict__ row_ptr,
                                                unsigned int* __restrict__ zb32) {
    const int lane = threadIdx.x & 63;
    const int wv = threadIdx.x >> 6;
    const int f2 = lane * 2;
    half2v wx[8], wy[8];
#pragma unroll
    for (int j = 0; j < 8; ++j) {
        wx[j] = u2h(wek[j * 128 + f2]);
        wy[j] = u2h(wek[j * 128 + f2 + 1]);
    }
    const float2 eb = *(const float2*)&be[f2];

    const int n = blockIdx.x * 4 + wv;        // grid exact: 12500*4 = 50000
    const int base = __builtin_amdgcn_readfirstlane(row_ptr[n]);
    const int deg = __builtin_amdgcn_readfirstlane(row_ptr[n + 1]) - base;

    const unsigned int hself = hb32[n * 64 + lane];
    float2 acc = make_float2(bfl(hself), bfh(hself));

    if (deg > 0) {
        const int* sp = src_s + base;
        const uint4* ep = eattr_h + (size_t)base * 2;
        const int last = deg - 1;
        const int nch = (deg + 3) >> 2;

        unsigned int huC[4], huN[4];
        uint4 eaC[4][2], eaN[4][2];
        int s2[4];
        {
            int s0[4], s1[4];
#pragma unroll
            for (int j = 0; j < 4; ++j) s0[j] = sp[min(j, last)];
#pragma unroll
            for (int j = 0; j < 4; ++j) huC[j] = hb32[s0[j] * 64 + lane];
#pragma unroll
            for (int j = 0; j < 4; ++j) s1[j] = sp[min(4 + j, last)];
            if (nch > 1) {
#pragma unroll
                for (int j = 0; j < 4; ++j) huN[j] = hb32[s1[j] * 64 + lane];
            } else {
#pragma unroll
                for (int j = 0; j < 4; ++j) huN[j] = 0u;
            }
#pragma unroll
            for (int j = 0; j < 4; ++j) {
                const int e = min(j, last);
                eaC[j][0] = ep[e * 2]; eaC[j][1] = ep[e * 2 + 1];
            }
#pragma unroll
            for (int j = 0; j < 4; ++j) s2[j] = sp[min(8 + j, last)];
        }
        for (int c = 0; c < nch; ++c) {
            // issue gathers for chunk c+2 (srcs loaded 2 iters ago)
            unsigned int huNN[4] = {0u, 0u, 0u, 0u};
            if (c + 2 < nch) {
#pragma unroll
                for (int j = 0; j < 4; ++j) huNN[j] = hb32[s2[j] * 64 + lane];
            }
            // srcs for chunk c+3 (uniform sequential)
            int s3[4];
#pragma unroll
            for (int j = 0; j < 4; ++j) s3[j] = sp[min((c + 3) * 4 + j, last)];
            // attrs for chunk c+1 (uniform sequential)
            if (c + 1 < nch) {
#pragma unroll
                for (int j = 0; j < 4; ++j) {
                    const int e = min((c + 1) * 4 + j, last);
                    eaN[j][0] = ep[e * 2]; eaN[j][1] = ep[e * 2 + 1];
                }
            }
            // compute chunk c
            const int rem = deg - c * 4;
#pragma unroll
            for (int j = 0; j < 4; ++j) {
                if (j < rem) {
                    const unsigned int* au = (const unsigned int*)&eaC[j][0];
                    float ex = eb.x, ey = eb.y;
#pragma unroll
                    for (int k = 0; k < 8; ++k) {
                        const half2v a = u2h(au[k]);
                        ex = __builtin_amdgcn_fdot2(a, wx[k], ex, false);
                        ey = __builtin_amdgcn_fdot2(a, wy[k], ey, false);
                    }
                    acc.x += fmaxf(bfl(huC[j]) + ex, 0.f);
                    acc.y += fmaxf(bfh(huC[j]) + ey, 0.f);
                }
            }
            // rotate pipeline (only if there is a next iteration)
            if (c + 1 < nch) {
#pragma unroll
                for (int j = 0; j < 4; ++j) {
                    huC[j] = huN[j]; huN[j] = huNN[j];
                    eaC[j][0] = eaN[j][0]; eaC[j][1] = eaN[j][1];
                    s2[j] = s3[j];
                }
            }
        }
    }
    zb32[n * 64 + lane] = pack2(acc.x, acc.y);
}

// ---------------------------------------------------------------------------
// Fused node MLP via bf16 MFMA (16x16x32): z2b = bf16(relu(z@W1+b1)@W2+b2),
// plus BN sum/sumsq partials (fp32, from accumulators).
// ---------------------------------------------------------------------------
#define Z1LD 136

__global__ __launch_bounds__(256, 3) void k_mlp(const unsigned short* __restrict__ zb,
                                                const unsigned short* __restrict__ w1p,
                                                const float* __restrict__ b1,
                                                const unsigned short* __restrict__ w2p,
                                                const float* __restrict__ b2,
                                                unsigned short* __restrict__ z2b,
                                                float* __restrict__ bn) {
    __shared__ unsigned short z1s[64 * Z1LD];
    __shared__ float redA[512];
    __shared__ float redB[512];
    const int tid = threadIdx.x;
    const int w = tid >> 6, lane = tid & 63;
    const int q = lane >> 4, l15 = lane & 15;
    const int row0 = blockIdx.x * 64 + w * 16;

    const int ar = min(row0 + l15, N_NODES - 1);
    const unsigned short* aptr = zb + (size_t)ar * HID + q * 8;

    f32x4 acc[8];
#pragma unroll
    for (int nt = 0; nt < 8; ++nt) acc[nt] = (f32x4){0.f, 0.f, 0.f, 0.f};

#pragma unroll
    for (int ks = 0; ks < 4; ++ks) {
        const short8 a = *(const short8*)(aptr + ks * 32);
#pragma unroll
        for (int nt = 0; nt < 8; ++nt) {
            const short8 b = *(const short8*)(w1p + (((ks << 3) + nt) * 64 + lane) * 8);
            acc[nt] = __builtin_amdgcn_mfma_f32_16x16x32_bf16(a, b, acc[nt], 0, 0, 0);
        }
    }
    {
        const int lr0 = w * 16 + q * 4;
#pragma unroll
        for (int nt = 0; nt < 8; ++nt) {
            const float bias = b1[nt * 16 + l15];
            const int cc = nt * 16 + l15;
#pragma unroll
            for (int reg = 0; reg < 4; ++reg) {
                const float v = fmaxf(acc[nt][reg] + bias, 0.f);
                z1s[(lr0 + reg) * Z1LD + cc] = (unsigned short)f2bf(v);
            }
        }
    }
#pragma unroll
    for (int nt = 0; nt < 8; ++nt) acc[nt] = (f32x4){0.f, 0.f, 0.f, 0.f};
    const unsigned short* a2p = &z1s[(w * 16 + l15) * Z1LD + q * 8];
#pragma unroll
    for (int ks = 0; ks < 4; ++ks) {
        const short8 a = *(const short8*)(a2p + ks * 32);
#pragma unroll
        for (int nt = 0; nt < 8; ++nt) {
            const short8 b = *(const short8*)(w2p + (((ks << 3) + nt) * 64 + lane) * 8);
            acc[nt] = __builtin_amdgcn_mfma_f32_16x16x32_bf16(a, b, acc[nt], 0, 0, 0);
        }
    }
    float s[8], sq[8];
    const int rowb = row0 + q * 4;
#pragma unroll
    for (int nt = 0; nt < 8; ++nt) {
        const float bias = b2[nt * 16 + l15];
        const int cc = nt * 16 + l15;
        float ls = 0.f, lq = 0.f;
#pragma unroll
        for (int reg = 0; reg < 4; ++reg) {
            const int r = rowb + reg;
            const float v = acc[nt][reg] + bias;
            if (r < N_NODES) {
                z2b[(size_t)r * HID + cc] = (unsigned short)f2bf(v);
                ls += v;
                lq = fmaf(v, v, lq);
            }
        }
        s[nt] = ls; sq[nt] = lq;
    }
#pragma unroll
    for (int nt = 0; nt < 8; ++nt) {
        s[nt] += __shfl_xor(s[nt], 16, 64);
        s[nt] += __shfl_xor(s[nt], 32, 64);
        sq[nt] += __shfl_xor(sq[nt], 16, 64);
        sq[nt] += __shfl_xor(sq[nt], 32, 64);
    }
    if (lane < 16) {
#pragma unroll
        for (int nt = 0; nt < 8; ++nt) {
            redA[w * 128 + nt * 16 + lane] = s[nt];
            redB[w * 128 + nt * 16 + lane] = sq[nt];
        }
    }
    __syncthreads();
    if (tid < 128) {
        float t = redA[tid] + redA[128 + tid] + redA[256 + tid] + redA[384 + tid];
        atomicAdd(&bn[tid], t);
    } else {
        const int c = tid - 128;
        float t = redB[c] + redB[128 + c] + redB[256 + c] + redB[384 + c];
        atomicAdd(&bn[128 + c], t);
    }
}

// ---------------------------------------------------------------------------
// BN (batch stats) + ReLU -> bf16 h (reads bf16 z2)
// ---------------------------------------------------------------------------
__global__ __launch_bounds__(256) void k_bnrelu(const unsigned short* __restrict__ z2b,
                                                const float* __restrict__ bn,
                                                const float* __restrict__ gamma,
                                                const float* __restrict__ beta,
                                                unsigned short* __restrict__ hb) {
    const int idx = (blockIdx.x * 256 + threadIdx.x) * 4;   // exact: 6250*256*4 = 6.4M
    const int c = idx & 127;
    const float invN = 1.0f / (float)N_NODES;
    const uint2 zz = *(const uint2*)(z2b + idx);
    float o[4] = {bfl(zz.x), bfh(zz.x), bfl(zz.y), bfh(zz.y)};
#pragma unroll
    for (int k = 0; k < 4; ++k) {
        const float m = bn[c + k] * invN;
        float var = bn[128 + c + k] * invN - m * m;
        var = fmaxf(var, 0.f);
        const float r = rsqrtf(var + BN_EPS);
        o[k] = fmaxf(gamma[c + k] * (o[k] - m) * r + beta[c + k], 0.f);
    }
    *(uint2*)&hb[idx] = make_uint2(pack2(o[0], o[1]), pack2(o[2], o[3]));
}

// ---------------------------------------------------------------------------
// Global add pool (batch is sorted): register accumulate, flush on change.
// ---------------------------------------------------------------------------
__global__ void k_pool(const unsigned short* __restrict__ hb, const int* __restrict__ batch,
                       float* __restrict__ g) {
    const int f = threadIdx.x;            // 128 threads
    const int n0 = blockIdx.x * 128;
    const int nend = min(n0 + 128, N_NODES);
    float acc = 0.f;
    int cur = batch[n0];
    for (int n = n0; n < nend; ++n) {
        const int bb = batch[n];
        if (bb != cur) {
            atomicAdd(&g[cur * HID + f], acc);
            acc = 0.f;
            cur = bb;
        }
        acc += bfl((unsigned int)hb[n * HID + f]);
    }
    atomicAdd(&g[cur * HID + f], acc);
}

// ---------------------------------------------------------------------------
// Head
// ---------------------------------------------------------------------------
__global__ void k_head1(const float* __restrict__ g, const float* __restrict__ W,
                        const float* __restrict__ b, float* __restrict__ g1) {
    const int idx = blockIdx.x * 256 + threadIdx.x;   // 32*256 = 8192
    const int r = idx >> 7, c = idx & 127;
    float acc = b[c];
    for (int k = 0; k < 128; ++k) acc = fmaf(g[r * HID + k], W[k * HID + c], acc);
    g1[idx] = fmaxf(acc, 0.f);
}

__global__ void k_head2(const float* __restrict__ g1, const float* __restrict__ W,
                        const float* __restrict__ b, float* __restrict__ out) {
    const int idx = threadIdx.x;          // 128
    const int r = idx >> 1, c = idx & 1;
    float acc = b[c];
    for (int k = 0; k < 128; ++k) acc = fmaf(g1[r * HID + k], W[k * 2 + c], acc);
    out[idx] = acc;
}

// ---------------------------------------------------------------------------
// Launch
// ---------------------------------------------------------------------------
extern "C" void kernel_launch(void* const* d_in, const int* in_sizes, int n_in,
                              void* d_out, int out_size, void* d_ws, size_t ws_size,
                              hipStream_t stream) {
    const float* x     = (const float*)d_in[0];
    const int*   ei    = (const int*)d_in[1];
    const float* eattr = (const float*)d_in[2];
    const int*   batch = (const int*)d_in[3];
    const float* encW  = (const float*)d_in[4];
    const float* encb  = (const float*)d_in[5];
    const float* eW    = (const float*)d_in[6];
    const float* eb    = (const float*)d_in[7];
    const float* W1    = (const float*)d_in[8];
    const float* b1    = (const float*)d_in[9];
    const float* W2    = (const float*)d_in[10];
    const float* b2    = (const float*)d_in[11];
    const float* gam   = (const float*)d_in[12];
    const float* bet   = (const float*)d_in[13];
    const float* hW1   = (const float*)d_in[14];
    const float* hb1   = (const float*)d_in[15];
    const float* hW2   = (const float*)d_in[16];
    const float* hb2   = (const float*)d_in[17];
    float* out = (float*)d_out;

    // workspace layout (float-sized slots); total ~71 MB
    float* ws = (float*)d_ws;
    unsigned short* z2b = (unsigned short*)ws;              // 6.4M u16 = 3.2M floats
    float* bn  = ws + 3200000;              // 256
    float* g   = ws + 3200256;              // 8,192
    float* g1  = ws + 3208448;              // 8,192
    unsigned short* hb = (unsigned short*)(ws + 3216640);   // 6.4M u16
    unsigned int* zb32 = (unsigned int*)(ws + 6416640);     // 6.4M u16
    unsigned int* xb32 = (unsigned int*)(ws + 9616640);     // 3.2M u16 = 1.6M floats
    int* row_ptr = (int*)(ws + 11216640);   // 50,001
    int* cursor  = row_ptr + N_NODES + 1;   // 50,000
    int* elist   = cursor + N_NODES;        // 640,000
    int* bsums   = elist + N_EDGES;         // 256
    int* src_s   = bsums + 256;             // 640,000 (ends 12,596,897)
    uint4* eattr_h = (uint4*)(ws + 12596900);               // 5.12M u32
    unsigned short* wp  = (unsigned short*)(ws + 17716900); // 98,304 u16
    unsigned short* wpe = (unsigned short*)(ws + 17766100); // 8,192 u16
    unsigned int*   wek = (unsigned int*)(ws + 17770200);   // 3,072 u32

    const int* esrc = ei;
    const int* edst = ei + N_EDGES;

    // CSR build + edge materialization (per call)
    hipMemsetAsync(row_ptr, 0, (N_NODES + 1) * sizeof(int), stream);
    k_hist<<<N_EDGES / 256, 256, 0, stream>>>(edst, row_ptr);
    k_blockred<<<196, 256, 0, stream>>>(row_ptr, bsums);
    k_scan_bsums<<<1, 64, 0, stream>>>(bsums, 196);
    k_scan_blocks<<<196, 256, 0, stream>>>(row_ptr, bsums, cursor);
    k_fill<<<N_EDGES / 256, 256, 0, stream>>>(edst, cursor, elist);
    k_gather<<<N_EDGES / 256, 256, 0, stream>>>(elist, esrc, eattr, src_s, eattr_h);

    // weight packing
    k_packW<<<48, 256, 0, stream>>>(W1, W2, wp);
    k_packEnc<<<4, 256, 0, stream>>>(encW, wpe);
    k_packWe<<<12, 256, 0, stream>>>(eW, wek);

    // encoder -> bf16 h (MFMA)
    k_xcast<<<6250, 256, 0, stream>>>(x, xb32);
    k_encm<<<782, 256, 0, stream>>>((const unsigned short*)xb32, wpe, encb, hb);

    for (int l = 0; l < N_LAYERS; ++l) {
        k_agg<<<12500, 256, 0, stream>>>((const unsigned int*)hb, src_s, eattr_h,
                                         wek + l * 1024, eb + l * HID, row_ptr, zb32);
        hipMemsetAsync(bn, 0, 256 * sizeof(float), stream);
        k_mlp<<<782, 256, 0, stream>>>((const unsigned short*)zb32,
                                       wp + (size_t)l * 16384, b1 + l * HID,
                                       wp + (size_t)(3 + l) * 16384, b2 + l * HID,
                                       z2b, bn);
        k_bnrelu<<<6250, 256, 0, stream>>>(z2b, bn, gam + l * HID, bet + l * HID, hb);
    }

    hipMemsetAsync(g, 0, NUM_GRAPHS * HID * sizeof(float), stream);
    k_pool<<<391, 128, 0, stream>>>(hb, batch, g);
    k_head1<<<32, 256, 0, stream>>>(g, hW1, hb1, g1);
    k_head2<<<1, 128, 0, stream>>>(g1, hW2, hb2, out);
}

// Round 8
// 608.860 us; speedup vs baseline: 1.7720x; 1.0007x over previous
//
#include <hip/hip_runtime.h>
#include <hip/hip_bf16.h>

// Problem constants (from reference)
#define N_NODES 50000
#define N_EDGES 640000
#define F_IN 64
#define EDGE_DIM 16
#define HID 128
#define N_LAYERS 3
#define NUM_GRAPHS 64
#define BN_EPS 1e-5f

#define AGG_BLOCKS 2048
#define AGG_WAVES (AGG_BLOCKS * 4)

typedef __attribute__((ext_vector_type(8))) short short8;    // 8 bf16 (4 VGPRs)
typedef __attribute__((ext_vector_type(4))) float f32x4;     // MFMA acc
typedef __attribute__((ext_vector_type(2))) __fp16 half2v;   // packed f16 pair (builtin type)

// bf16 <-> f32 helpers (manual, RNE on pack)
__device__ __forceinline__ float bfl(unsigned int u) {
    unsigned int v = u << 16; float f; __builtin_memcpy(&f, &v, 4); return f;
}
__device__ __forceinline__ float bfh(unsigned int u) {
    unsigned int v = u & 0xffff0000u; float f; __builtin_memcpy(&f, &v, 4); return f;
}
__device__ __forceinline__ unsigned int f2bf(float f) {
    unsigned int v; __builtin_memcpy(&v, &f, 4);
    v += 0x7fffu + ((v >> 16) & 1u);
    return v >> 16;
}
__device__ __forceinline__ unsigned int pack2(float lo, float hi) {
    return f2bf(lo) | (f2bf(hi) << 16);
}
__device__ __forceinline__ half2v u2h(unsigned int u) {
    half2v h; __builtin_memcpy(&h, &u, 4); return h;
}
__device__ __forceinline__ unsigned int pkh(float a, float b) {
    half2v h = __builtin_amdgcn_cvt_pkrtz(a, b);
    unsigned int u; __builtin_memcpy(&u, &h, 4); return u;
}

// ---------------------------------------------------------------------------
// CSR build
// ---------------------------------------------------------------------------
__global__ void k_hist(const int* __restrict__ dst, int* __restrict__ deg) {
    int e = blockIdx.x * 256 + threadIdx.x;   // grid exact: 2500*256 = 640000
    atomicAdd(&deg[dst[e]], 1);
}

__global__ void k_blockred(const int* __restrict__ deg, int* __restrict__ bsums) {
    __shared__ int s[256];
    int i = blockIdx.x * 256 + threadIdx.x;
    int v = (i < N_NODES) ? deg[i] : 0;
    s[threadIdx.x] = v;
    __syncthreads();
    for (int off = 128; off > 0; off >>= 1) {
        if (threadIdx.x < off) s[threadIdx.x] += s[threadIdx.x + off];
        __syncthreads();
    }
    if (threadIdx.x == 0) bsums[blockIdx.x] = s[0];
}

// parallel exclusive scan of block sums (nb <= 256, one block)
__global__ void k_scan_bsums(int* __restrict__ bsums, int nb) {
    __shared__ int s[256];
    const int tid = threadIdx.x;
    const int v = (tid < nb) ? bsums[tid] : 0;
    s[tid] = v;
    __syncthreads();
    for (int off = 1; off < 256; off <<= 1) {
        int t = 0;
        if (tid >= off) t = s[tid - off];
        __syncthreads();
        s[tid] += t;
        __syncthreads();
    }
    if (tid < nb) bsums[tid] = s[tid] - v;
}

__global__ void k_scan_blocks(int* __restrict__ deg_rowptr, const int* __restrict__ bsums,
                              int* __restrict__ cursor) {
    __shared__ int s[256];
    int tid = threadIdx.x;
    int i = blockIdx.x * 256 + tid;
    int v = (i < N_NODES) ? deg_rowptr[i] : 0;
    s[tid] = v;
    __syncthreads();
    for (int off = 1; off < 256; off <<= 1) {
        int t = 0;
        if (tid >= off) t = s[tid - off];
        __syncthreads();
        s[tid] += t;
        __syncthreads();
    }
    int excl = s[tid] - v + bsums[blockIdx.x];
    if (i < N_NODES) {
        deg_rowptr[i] = excl;
        cursor[i] = excl;
    }
    if (i == N_NODES - 1) deg_rowptr[N_NODES] = N_EDGES;
}

__global__ void k_fill(const int* __restrict__ dst, int* __restrict__ cursor,
                       int* __restrict__ elist) {
    int e = blockIdx.x * 256 + threadIdx.x;   // exact
    int p = atomicAdd(&cursor[dst[e]], 1);
    elist[p] = e;
}

// ---------------------------------------------------------------------------
// Edge materialization, 4 edges per thread (batched index->gather for MLP):
// src_s[p] = esrc[elist[p]]; eattr_h[p] = f16-pair packed eattr[elist[p]].
// Block covers 1024 consecutive CSR slots; thread j-th edge = tid + j*256.
// ---------------------------------------------------------------------------
__global__ __launch_bounds__(256) void k_gather(const int* __restrict__ elist,
                                                const int* __restrict__ esrc,
                                                const float* __restrict__ eattr,
                                                int* __restrict__ src_s,
                                                uint4* __restrict__ eattr_h) {
    const int base = blockIdx.x * 1024;       // grid exact: 625*1024 = 640000
    const int tid = threadIdx.x;
    int p[4], eid[4];
#pragma unroll
    for (int j = 0; j < 4; ++j) p[j] = base + tid + j * 256;
#pragma unroll
    for (int j = 0; j < 4; ++j) eid[j] = elist[p[j]];
    int sv[4];
#pragma unroll
    for (int j = 0; j < 4; ++j) sv[j] = esrc[eid[j]];
    float4 a[4][4];
#pragma unroll
    for (int j = 0; j < 4; ++j) {
        const float* ep = eattr + (size_t)eid[j] * EDGE_DIM;
        a[j][0] = *(const float4*)ep;
        a[j][1] = *(const float4*)(ep + 4);
        a[j][2] = *(const float4*)(ep + 8);
        a[j][3] = *(const float4*)(ep + 12);
    }
#pragma unroll
    for (int j = 0; j < 4; ++j) {
        src_s[p[j]] = sv[j];
        eattr_h[p[j] * 2] = make_uint4(pkh(a[j][0].x, a[j][0].y), pkh(a[j][0].z, a[j][0].w),
                                       pkh(a[j][1].x, a[j][1].y), pkh(a[j][1].z, a[j][1].w));
        eattr_h[p[j] * 2 + 1] = make_uint4(pkh(a[j][2].x, a[j][2].y), pkh(a[j][2].z, a[j][2].w),
                                           pkh(a[j][3].x, a[j][3].y), pkh(a[j][3].z, a[j][3].w));
    }
}

// ---------------------------------------------------------------------------
// Merged weight packing: [0,12288) = W1/W2 MFMA B-frags, [12288,13312) =
// enc_W B-frags, [13312,16384) = edge-weight f16 pairs.
// ---------------------------------------------------------------------------
__global__ void k_pack(const float* __restrict__ W1, const float* __restrict__ W2,
                       const float* __restrict__ encW, const float* __restrict__ eW,
                       unsigned short* __restrict__ wp, unsigned short* __restrict__ wpe,
                       unsigned int* __restrict__ wek) {
    const int t = blockIdx.x * 256 + threadIdx.x;   // 64*256 = 16384 exact
    if (t < 12288) {
        const int mat = t >> 11;
        const int r = t & 2047;
        const int kstep = r >> 9;
        const int ntile = (r >> 6) & 7;
        const int lane = r & 63;
        const float* W = (mat < 3) ? (W1 + mat * 16384) : (W2 + (mat - 3) * 16384);
        const int kbase = kstep * 32 + ((lane >> 4) << 3);
        const int n = ntile * 16 + (lane & 15);
        unsigned int o[4];
#pragma unroll
        for (int jj = 0; jj < 4; ++jj)
            o[jj] = pack2(W[(kbase + 2 * jj) * HID + n], W[(kbase + 2 * jj + 1) * HID + n]);
        *(uint4*)(wp + (size_t)mat * 16384 + (((kstep << 3) + ntile) * 64 + lane) * 8) =
            make_uint4(o[0], o[1], o[2], o[3]);
    } else if (t < 13312) {
        const int r = t - 12288;
        const int kstep = r >> 9;
        const int ntile = (r >> 6) & 7;
        const int lane = r & 63;
        const int kbase = kstep * 32 + ((lane >> 4) << 3);
        const int n = ntile * 16 + (lane & 15);
        unsigned int o[4];
#pragma unroll
        for (int jj = 0; jj < 4; ++jj)
            o[jj] = pack2(encW[(kbase + 2 * jj) * HID + n], encW[(kbase + 2 * jj + 1) * HID + n]);
        *(uint4*)(wpe + (((kstep << 3) + ntile) * 64 + lane) * 8) =
            make_uint4(o[0], o[1], o[2], o[3]);
    } else {
        const int r = t - 13312;                    // 0..3071
        const int l = r >> 10;
        const int rr = r & 1023;
        const int kp = rr >> 7, f = rr & 127;
        const float a = eW[(l * EDGE_DIM + 2 * kp) * HID + f];
        const float b = eW[(l * EDGE_DIM + 2 * kp + 1) * HID + f];
        wek[r] = pkh(a, b);
    }
}

// ---------------------------------------------------------------------------
// Encoder via MFMA: hb = bf16(x @ enc_W + enc_b), reads fp32 x directly.
// ---------------------------------------------------------------------------
__global__ __launch_bounds__(256, 3) void k_encm(const float* __restrict__ x,
                                                 const unsigned short* __restrict__ wpe,
                                                 const float* __restrict__ b,
                                                 unsigned short* __restrict__ hb) {
    const int tid = threadIdx.x;
    const int w = tid >> 6, lane = tid & 63;
    const int q = lane >> 4, l15 = lane & 15;
    const int row0 = blockIdx.x * 64 + w * 16;
    const int ar = min(row0 + l15, N_NODES - 1);
    const float* xp = x + (size_t)ar * F_IN + q * 8;
    f32x4 acc[8];
#pragma unroll
    for (int nt = 0; nt < 8; ++nt) acc[nt] = (f32x4){0.f, 0.f, 0.f, 0.f};
#pragma unroll
    for (int ks = 0; ks < 2; ++ks) {
        const float4 v0 = *(const float4*)(xp + ks * 32);
        const float4 v1 = *(const float4*)(xp + ks * 32 + 4);
        unsigned int u[4] = {pack2(v0.x, v0.y), pack2(v0.z, v0.w),
                             pack2(v1.x, v1.y), pack2(v1.z, v1.w)};
        short8 a; __builtin_memcpy(&a, u, 16);
#pragma unroll
        for (int nt = 0; nt < 8; ++nt) {
            const short8 bf = *(const short8*)(wpe + (((ks << 3) + nt) * 64 + lane) * 8);
            acc[nt] = __builtin_amdgcn_mfma_f32_16x16x32_bf16(a, bf, acc[nt], 0, 0, 0);
        }
    }
    const int rowb = row0 + q * 4;
#pragma unroll
    for (int nt = 0; nt < 8; ++nt) {
        const float bias = b[nt * 16 + l15];
        const int cc = nt * 16 + l15;
#pragma unroll
        for (int reg = 0; reg < 4; ++reg) {
            const int r = rowb + reg;
            if (r < N_NODES)
                hb[(size_t)r * HID + cc] = (unsigned short)f2bf(acc[nt][reg] + bias);
        }
    }
}

// ---------------------------------------------------------------------------
// GINE aggregation v7: grid-stride waves (full occupancy), per-node body
// unchanged: f16 dot2 edge-MLP, chunk-of-4 with depth-2 gather pipeline.
// ---------------------------------------------------------------------------
__global__ __launch_bounds__(256, 2) void k_agg(const unsigned int* __restrict__ hb32,
                                                const int* __restrict__ src_s,
                                                const uint4* __restrict__ eattr_h,
                                                const unsigned int* __restrict__ wek,
                                                const float* __restrict__ be,
                                                const int* __restrict__ row_ptr,
                                                unsigned int* __restrict__ zb32) {
    const int lane = threadIdx.x & 63;
    const int wv = threadIdx.x >> 6;
    const int f2 = lane * 2;
    half2v wx[8], wy[8];
#pragma unroll
    for (int j = 0; j < 8; ++j) {
        wx[j] = u2h(wek[j * 128 + f2]);
        wy[j] = u2h(wek[j * 128 + f2 + 1]);
    }
    const float2 eb = *(const float2*)&be[f2];
    const int wgid = blockIdx.x * 4 + wv;

    for (int n = wgid; n < N_NODES; n += AGG_WAVES) {
        const int base = __builtin_amdgcn_readfirstlane(row_ptr[n]);
        const int deg = __builtin_amdgcn_readfirstlane(row_ptr[n + 1]) - base;

        const unsigned int hself = hb32[n * 64 + lane];
        float2 acc = make_float2(bfl(hself), bfh(hself));

        if (deg > 0) {
            const int* sp = src_s + base;
            const uint4* ep = eattr_h + (size_t)base * 2;
            const int last = deg - 1;
            const int nch = (deg + 3) >> 2;

            unsigned int huC[4], huN[4];
            uint4 eaC[4][2], eaN[4][2];
            int s2[4];
            {
                int s0[4], s1[4];
#pragma unroll
                for (int j = 0; j < 4; ++j) s0[j] = sp[min(j, last)];
#pragma unroll
                for (int j = 0; j < 4; ++j) huC[j] = hb32[s0[j] * 64 + lane];
#pragma unroll
                for (int j = 0; j < 4; ++j) s1[j] = sp[min(4 + j, last)];
                if (nch > 1) {
#pragma unroll
                    for (int j = 0; j < 4; ++j) huN[j] = hb32[s1[j] * 64 + lane];
                } else {
#pragma unroll
                    for (int j = 0; j < 4; ++j) huN[j] = 0u;
                }
#pragma unroll
                for (int j = 0; j < 4; ++j) {
                    const int e = min(j, last);
                    eaC[j][0] = ep[e * 2]; eaC[j][1] = ep[e * 2 + 1];
                }
#pragma unroll
                for (int j = 0; j < 4; ++j) s2[j] = sp[min(8 + j, last)];
            }
            for (int c = 0; c < nch; ++c) {
                unsigned int huNN[4] = {0u, 0u, 0u, 0u};
                if (c + 2 < nch) {
#pragma unroll
                    for (int j = 0; j < 4; ++j) huNN[j] = hb32[s2[j] * 64 + lane];
                }
                int s3[4];
#pragma unroll
                for (int j = 0; j < 4; ++j) s3[j] = sp[min((c + 3) * 4 + j, last)];
                if (c + 1 < nch) {
#pragma unroll
                    for (int j = 0; j < 4; ++j) {
                        const int e = min((c + 1) * 4 + j, last);
                        eaN[j][0] = ep[e * 2]; eaN[j][1] = ep[e * 2 + 1];
                    }
                }
                const int rem = deg - c * 4;
#pragma unroll
                for (int j = 0; j < 4; ++j) {
                    if (j < rem) {
                        const unsigned int* au = (const unsigned int*)&eaC[j][0];
                        float ex = eb.x, ey = eb.y;
#pragma unroll
                        for (int k = 0; k < 8; ++k) {
                            const half2v a = u2h(au[k]);
                            ex = __builtin_amdgcn_fdot2(a, wx[k], ex, false);
                            ey = __builtin_amdgcn_fdot2(a, wy[k], ey, false);
                        }
                        acc.x += fmaxf(bfl(huC[j]) + ex, 0.f);
                        acc.y += fmaxf(bfh(huC[j]) + ey, 0.f);
                    }
                }
                if (c + 1 < nch) {
#pragma unroll
                    for (int j = 0; j < 4; ++j) {
                        huC[j] = huN[j]; huN[j] = huNN[j];
                        eaC[j][0] = eaN[j][0]; eaC[j][1] = eaN[j][1];
                        s2[j] = s3[j];
                    }
                }
            }
        }
        zb32[n * 64 + lane] = pack2(acc.x, acc.y);
    }
}

// ---------------------------------------------------------------------------
// Fused node MLP via bf16 MFMA (16x16x32): z2b = bf16(relu(z@W1+b1)@W2+b2),
// plus BN sum/sumsq partials (fp32, from accumulators).
// ---------------------------------------------------------------------------
#define Z1LD 136

__global__ __launch_bounds__(256, 3) void k_mlp(const unsigned short* __restrict__ zb,
                                                const unsigned short* __restrict__ w1p,
                                                const float* __restrict__ b1,
                                                const unsigned short* __restrict__ w2p,
                                                const float* __restrict__ b2,
                                                unsigned short* __restrict__ z2b,
                                                float* __restrict__ bn) {
    __shared__ unsigned short z1s[64 * Z1LD];
    __shared__ float redA[512];
    __shared__ float redB[512];
    const int tid = threadIdx.x;
    const int w = tid >> 6, lane = tid & 63;
    const int q = lane >> 4, l15 = lane & 15;
    const int row0 = blockIdx.x * 64 + w * 16;

    const int ar = min(row0 + l15, N_NODES - 1);
    const unsigned short* aptr = zb + (size_t)ar * HID + q * 8;

    f32x4 acc[8];
#pragma unroll
    for (int nt = 0; nt < 8; ++nt) acc[nt] = (f32x4){0.f, 0.f, 0.f, 0.f};

#pragma unroll
    for (int ks = 0; ks < 4; ++ks) {
        const short8 a = *(const short8*)(aptr + ks * 32);
#pragma unroll
        for (int nt = 0; nt < 8; ++nt) {
            const short8 b = *(const short8*)(w1p + (((ks << 3) + nt) * 64 + lane) * 8);
            acc[nt] = __builtin_amdgcn_mfma_f32_16x16x32_bf16(a, b, acc[nt], 0, 0, 0);
        }
    }
    {
        const int lr0 = w * 16 + q * 4;
#pragma unroll
        for (int nt = 0; nt < 8; ++nt) {
            const float bias = b1[nt * 16 + l15];
            const int cc = nt * 16 + l15;
#pragma unroll
            for (int reg = 0; reg < 4; ++reg) {
                const float v = fmaxf(acc[nt][reg] + bias, 0.f);
                z1s[(lr0 + reg) * Z1LD + cc] = (unsigned short)f2bf(v);
            }
        }
    }
#pragma unroll
    for (int nt = 0; nt < 8; ++nt) acc[nt] = (f32x4){0.f, 0.f, 0.f, 0.f};
    const unsigned short* a2p = &z1s[(w * 16 + l15) * Z1LD + q * 8];
#pragma unroll
    for (int ks = 0; ks < 4; ++ks) {
        const short8 a = *(const short8*)(a2p + ks * 32);
#pragma unroll
        for (int nt = 0; nt < 8; ++nt) {
            const short8 b = *(const short8*)(w2p + (((ks << 3) + nt) * 64 + lane) * 8);
            acc[nt] = __builtin_amdgcn_mfma_f32_16x16x32_bf16(a, b, acc[nt], 0, 0, 0);
        }
    }
    float s[8], sq[8];
    const int rowb = row0 + q * 4;
#pragma unroll
    for (int nt = 0; nt < 8; ++nt) {
        const float bias = b2[nt * 16 + l15];
        const int cc = nt * 16 + l15;
        float ls = 0.f, lq = 0.f;
#pragma unroll
        for (int reg = 0; reg < 4; ++reg) {
            const int r = rowb + reg;
            const float v = acc[nt][reg] + bias;
            if (r < N_NODES) {
                z2b[(size_t)r * HID + cc] = (unsigned short)f2bf(v);
                ls += v;
                lq = fmaf(v, v, lq);
            }
        }
        s[nt] = ls; sq[nt] = lq;
    }
#pragma unroll
    for (int nt = 0; nt < 8; ++nt) {
        s[nt] += __shfl_xor(s[nt], 16, 64);
        s[nt] += __shfl_xor(s[nt], 32, 64);
        sq[nt] += __shfl_xor(sq[nt], 16, 64);
        sq[nt] += __shfl_xor(sq[nt], 32, 64);
    }
    if (lane < 16) {
#pragma unroll
        for (int nt = 0; nt < 8; ++nt) {
            redA[w * 128 + nt * 16 + lane] = s[nt];
            redB[w * 128 + nt * 16 + lane] = sq[nt];
        }
    }
    __syncthreads();
    if (tid < 128) {
        float t = redA[tid] + redA[128 + tid] + redA[256 + tid] + redA[384 + tid];
        atomicAdd(&bn[tid], t);
    } else {
        const int c = tid - 128;
        float t = redB[c] + redB[128 + c] + redB[256 + c] + redB[384 + c];
        atomicAdd(&bn[128 + c], t);
    }
}

// ---------------------------------------------------------------------------
// BN (batch stats) + ReLU -> bf16 h (reads bf16 z2)
// ---------------------------------------------------------------------------
__global__ __launch_bounds__(256) void k_bnrelu(const unsigned short* __restrict__ z2b,
                                                const float* __restrict__ bn,
                                                const float* __restrict__ gamma,
                                                const float* __restrict__ beta,
                                                unsigned short* __restrict__ hb) {
    const int idx = (blockIdx.x * 256 + threadIdx.x) * 4;   // exact: 6250*256*4 = 6.4M
    const int c = idx & 127;
    const float invN = 1.0f / (float)N_NODES;
    const uint2 zz = *(const uint2*)(z2b + idx);
    float o[4] = {bfl(zz.x), bfh(zz.x), bfl(zz.y), bfh(zz.y)};
#pragma unroll
    for (int k = 0; k < 4; ++k) {
        const float m = bn[c + k] * invN;
        float var = bn[128 + c + k] * invN - m * m;
        var = fmaxf(var, 0.f);
        const float r = rsqrtf(var + BN_EPS);
        o[k] = fmaxf(gamma[c + k] * (o[k] - m) * r + beta[c + k], 0.f);
    }
    *(uint2*)&hb[idx] = make_uint2(pack2(o[0], o[1]), pack2(o[2], o[3]));
}

// ---------------------------------------------------------------------------
// Global add pool (batch is sorted): register accumulate, flush on change.
// ---------------------------------------------------------------------------
__global__ void k_pool(const unsigned short* __restrict__ hb, const int* __restrict__ batch,
                       float* __restrict__ g) {
    const int f = threadIdx.x;            // 128 threads
    const int n0 = blockIdx.x * 128;
    const int nend = min(n0 + 128, N_NODES);
    float acc = 0.f;
    int cur = batch[n0];
    for (int n = n0; n < nend; ++n) {
        const int bb = batch[n];
        if (bb != cur) {
            atomicAdd(&g[cur * HID + f], acc);
            acc = 0.f;
            cur = bb;
        }
        acc += bfl((unsigned int)hb[n * HID + f]);
    }
    atomicAdd(&g[cur * HID + f], acc);
}

// ---------------------------------------------------------------------------
// Head
// ---------------------------------------------------------------------------
__global__ void k_head1(const float* __restrict__ g, const float* __restrict__ W,
                        const float* __restrict__ b, float* __restrict__ g1) {
    const int idx = blockIdx.x * 256 + threadIdx.x;   // 32*256 = 8192
    const int r = idx >> 7, c = idx & 127;
    float acc = b[c];
    for (int k = 0; k < 128; ++k) acc = fmaf(g[r * HID + k], W[k * HID + c], acc);
    g1[idx] = fmaxf(acc, 0.f);
}

__global__ void k_head2(const float* __restrict__ g1, const float* __restrict__ W,
                        const float* __restrict__ b, float* __restrict__ out) {
    const int idx = threadIdx.x;          // 128
    const int r = idx >> 1, c = idx & 1;
    float acc = b[c];
    for (int k = 0; k < 128; ++k) acc = fmaf(g1[r * HID + k], W[k * 2 + c], acc);
    out[idx] = acc;
}

// ---------------------------------------------------------------------------
// Launch
// ---------------------------------------------------------------------------
extern "C" void kernel_launch(void* const* d_in, const int* in_sizes, int n_in,
                              void* d_out, int out_size, void* d_ws, size_t ws_size,
                              hipStream_t stream) {
    const float* x     = (const float*)d_in[0];
    const int*   ei    = (const int*)d_in[1];
    const float* eattr = (const float*)d_in[2];
    const int*   batch = (const int*)d_in[3];
    const float* encW  = (const float*)d_in[4];
    const float* encb  = (const float*)d_in[5];
    const float* eW    = (const float*)d_in[6];
    const float* eb    = (const float*)d_in[7];
    const float* W1    = (const float*)d_in[8];
    const float* b1    = (const float*)d_in[9];
    const float* W2    = (const float*)d_in[10];
    const float* b2    = (const float*)d_in[11];
    const float* gam   = (const float*)d_in[12];
    const float* bet   = (const float*)d_in[13];
    const float* hW1   = (const float*)d_in[14];
    const float* hb1   = (const float*)d_in[15];
    const float* hW2   = (const float*)d_in[16];
    const float* hb2   = (const float*)d_in[17];
    float* out = (float*)d_out;

    // workspace layout (float-sized slots)
    float* ws = (float*)d_ws;
    unsigned short* z2b = (unsigned short*)ws;              // 6.4M u16 = 3.2M floats
    float* bn  = ws + 3200000;              // 256
    float* g   = ws + 3200256;              // 8,192
    float* g1  = ws + 3208448;              // 8,192
    unsigned short* hb = (unsigned short*)(ws + 3216640);   // 6.4M u16
    unsigned int* zb32 = (unsigned int*)(ws + 6416640);     // 6.4M u16
    int* row_ptr = (int*)(ws + 11216640);   // 50,001
    int* cursor  = row_ptr + N_NODES + 1;   // 50,000
    int* elist   = cursor + N_NODES;        // 640,000
    int* bsums   = elist + N_EDGES;         // 256
    int* src_s   = bsums + 256;             // 640,000
    uint4* eattr_h = (uint4*)(ws + 12596900);               // 5.12M u32
    unsigned short* wp  = (unsigned short*)(ws + 17716900); // 98,304 u16
    unsigned short* wpe = (unsigned short*)(ws + 17766100); // 8,192 u16
    unsigned int*   wek = (unsigned int*)(ws + 17770200);   // 3,072 u32

    const int* esrc = ei;
    const int* edst = ei + N_EDGES;

    // CSR build + edge materialization (per call)
    hipMemsetAsync(row_ptr, 0, (N_NODES + 1) * sizeof(int), stream);
    k_hist<<<N_EDGES / 256, 256, 0, stream>>>(edst, row_ptr);
    k_blockred<<<196, 256, 0, stream>>>(row_ptr, bsums);
    k_scan_bsums<<<1, 256, 0, stream>>>(bsums, 196);
    k_scan_blocks<<<196, 256, 0, stream>>>(row_ptr, bsums, cursor);
    k_fill<<<N_EDGES / 256, 256, 0, stream>>>(edst, cursor, elist);
    k_gather<<<N_EDGES / 1024, 256, 0, stream>>>(elist, esrc, eattr, src_s, eattr_h);

    // merged weight packing
    k_pack<<<64, 256, 0, stream>>>(W1, W2, encW, eW, wp, wpe, wek);

    // encoder -> bf16 h (MFMA, reads fp32 x directly)
    k_encm<<<782, 256, 0, stream>>>(x, wpe, encb, hb);

    for (int l = 0; l < N_LAYERS; ++l) {
        k_agg<<<AGG_BLOCKS, 256, 0, stream>>>((const unsigned int*)hb, src_s, eattr_h,
                                              wek + l * 1024, eb + l * HID, row_ptr, zb32);
        hipMemsetAsync(bn, 0, 256 * sizeof(float), stream);
        k_mlp<<<782, 256, 0, stream>>>((const unsigned short*)zb32,
                                       wp + (size_t)l * 16384, b1 + l * HID,
                                       wp + (size_t)(3 + l) * 16384, b2 + l * HID,
                                       z2b, bn);
        k_bnrelu<<<6250, 256, 0, stream>>>(z2b, bn, gam + l * HID, bet + l * HID, hb);
    }

    hipMemsetAsync(g, 0, NUM_GRAPHS * HID * sizeof(float), stream);
    k_pool<<<391, 128, 0, stream>>>(hb, batch, g);
    k_head1<<<32, 256, 0, stream>>>(g, hW1, hb1, g1);
    k_head2<<<1, 128, 0, stream>>>(g1, hW2, hb2, out);
}

// Round 9
// 571.053 us; speedup vs baseline: 1.8894x; 1.0662x over previous
//
#include <hip/hip_runtime.h>
#include <hip/hip_bf16.h>

// Problem constants (from reference)
#define N_NODES 50000
#define N_EDGES 640000
#define F_IN 64
#define EDGE_DIM 16
#define HID 128
#define N_LAYERS 3
#define NUM_GRAPHS 64
#define BN_EPS 1e-5f

typedef __attribute__((ext_vector_type(8))) short short8;    // 8 bf16 (4 VGPRs)
typedef __attribute__((ext_vector_type(4))) float f32x4;     // MFMA acc
typedef __attribute__((ext_vector_type(2))) __fp16 half2v;   // packed f16 pair (builtin type)

// bf16 <-> f32 helpers (manual, RNE on pack)
__device__ __forceinline__ float bfl(unsigned int u) {
    unsigned int v = u << 16; float f; __builtin_memcpy(&f, &v, 4); return f;
}
__device__ __forceinline__ float bfh(unsigned int u) {
    unsigned int v = u & 0xffff0000u; float f; __builtin_memcpy(&f, &v, 4); return f;
}
__device__ __forceinline__ unsigned int f2bf(float f) {
    unsigned int v; __builtin_memcpy(&v, &f, 4);
    v += 0x7fffu + ((v >> 16) & 1u);
    return v >> 16;
}
__device__ __forceinline__ unsigned int pack2(float lo, float hi) {
    return f2bf(lo) | (f2bf(hi) << 16);
}
__device__ __forceinline__ half2v u2h(unsigned int u) {
    half2v h; __builtin_memcpy(&h, &u, 4); return h;
}
__device__ __forceinline__ unsigned int pkh(float a, float b) {
    half2v h = __builtin_amdgcn_cvt_pkrtz(a, b);
    unsigned int u; __builtin_memcpy(&u, &h, 4); return u;
}

// ---------------------------------------------------------------------------
// CSR build
// ---------------------------------------------------------------------------
__global__ void k_hist(const int* __restrict__ dst, int* __restrict__ deg) {
    int e = blockIdx.x * 256 + threadIdx.x;   // grid exact: 2500*256 = 640000
    atomicAdd(&deg[dst[e]], 1);
}

__global__ void k_blockred(const int* __restrict__ deg, int* __restrict__ bsums) {
    __shared__ int s[256];
    int i = blockIdx.x * 256 + threadIdx.x;
    int v = (i < N_NODES) ? deg[i] : 0;
    s[threadIdx.x] = v;
    __syncthreads();
    for (int off = 128; off > 0; off >>= 1) {
        if (threadIdx.x < off) s[threadIdx.x] += s[threadIdx.x + off];
        __syncthreads();
    }
    if (threadIdx.x == 0) bsums[blockIdx.x] = s[0];
}

// parallel exclusive scan of block sums (nb <= 256, one block)
__global__ void k_scan_bsums(int* __restrict__ bsums, int nb) {
    __shared__ int s[256];
    const int tid = threadIdx.x;
    const int v = (tid < nb) ? bsums[tid] : 0;
    s[tid] = v;
    __syncthreads();
    for (int off = 1; off < 256; off <<= 1) {
        int t = 0;
        if (tid >= off) t = s[tid - off];
        __syncthreads();
        s[tid] += t;
        __syncthreads();
    }
    if (tid < nb) bsums[tid] = s[tid] - v;
}

__global__ void k_scan_blocks(int* __restrict__ deg_rowptr, const int* __restrict__ bsums,
                              int* __restrict__ cursor) {
    __shared__ int s[256];
    int tid = threadIdx.x;
    int i = blockIdx.x * 256 + tid;
    int v = (i < N_NODES) ? deg_rowptr[i] : 0;
    s[tid] = v;
    __syncthreads();
    for (int off = 1; off < 256; off <<= 1) {
        int t = 0;
        if (tid >= off) t = s[tid - off];
        __syncthreads();
        s[tid] += t;
        __syncthreads();
    }
    int excl = s[tid] - v + bsums[blockIdx.x];
    if (i < N_NODES) {
        deg_rowptr[i] = excl;
        cursor[i] = excl;
    }
    if (i == N_NODES - 1) deg_rowptr[N_NODES] = N_EDGES;
}

__global__ void k_fill(const int* __restrict__ dst, int* __restrict__ cursor,
                       int* __restrict__ elist) {
    int e = blockIdx.x * 256 + threadIdx.x;   // exact
    int p = atomicAdd(&cursor[dst[e]], 1);
    elist[p] = e;
}

// ---------------------------------------------------------------------------
// Edge materialization, 4 edges per thread (batched index->gather for MLP):
// src_s[p] = esrc[elist[p]]; eattr_h[p] = f16-pair packed eattr[elist[p]].
// ---------------------------------------------------------------------------
__global__ __launch_bounds__(256) void k_gather(const int* __restrict__ elist,
                                                const int* __restrict__ esrc,
                                                const float* __restrict__ eattr,
                                                int* __restrict__ src_s,
                                                uint4* __restrict__ eattr_h) {
    const int base = blockIdx.x * 1024;       // grid exact: 625*1024 = 640000
    const int tid = threadIdx.x;
    int p[4], eid[4];
#pragma unroll
    for (int j = 0; j < 4; ++j) p[j] = base + tid + j * 256;
#pragma unroll
    for (int j = 0; j < 4; ++j) eid[j] = elist[p[j]];
    int sv[4];
#pragma unroll
    for (int j = 0; j < 4; ++j) sv[j] = esrc[eid[j]];
    float4 a[4][4];
#pragma unroll
    for (int j = 0; j < 4; ++j) {
        const float* ep = eattr + (size_t)eid[j] * EDGE_DIM;
        a[j][0] = *(const float4*)ep;
        a[j][1] = *(const float4*)(ep + 4);
        a[j][2] = *(const float4*)(ep + 8);
        a[j][3] = *(const float4*)(ep + 12);
    }
#pragma unroll
    for (int j = 0; j < 4; ++j) {
        src_s[p[j]] = sv[j];
        eattr_h[p[j] * 2] = make_uint4(pkh(a[j][0].x, a[j][0].y), pkh(a[j][0].z, a[j][0].w),
                                       pkh(a[j][1].x, a[j][1].y), pkh(a[j][1].z, a[j][1].w));
        eattr_h[p[j] * 2 + 1] = make_uint4(pkh(a[j][2].x, a[j][2].y), pkh(a[j][2].z, a[j][2].w),
                                           pkh(a[j][3].x, a[j][3].y), pkh(a[j][3].z, a[j][3].w));
    }
}

// ---------------------------------------------------------------------------
// Merged weight packing: [0,12288) = W1/W2 MFMA B-frags, [12288,13312) =
// enc_W B-frags, [13312,16384) = edge-weight f16 pairs.
// ---------------------------------------------------------------------------
__global__ void k_pack(const float* __restrict__ W1, const float* __restrict__ W2,
                       const float* __restrict__ encW, const float* __restrict__ eW,
                       unsigned short* __restrict__ wp, unsigned short* __restrict__ wpe,
                       unsigned int* __restrict__ wek) {
    const int t = blockIdx.x * 256 + threadIdx.x;   // 64*256 = 16384 exact
    if (t < 12288) {
        const int mat = t >> 11;
        const int r = t & 2047;
        const int kstep = r >> 9;
        const int ntile = (r >> 6) & 7;
        const int lane = r & 63;
        const float* W = (mat < 3) ? (W1 + mat * 16384) : (W2 + (mat - 3) * 16384);
        const int kbase = kstep * 32 + ((lane >> 4) << 3);
        const int n = ntile * 16 + (lane & 15);
        unsigned int o[4];
#pragma unroll
        for (int jj = 0; jj < 4; ++jj)
            o[jj] = pack2(W[(kbase + 2 * jj) * HID + n], W[(kbase + 2 * jj + 1) * HID + n]);
        *(uint4*)(wp + (size_t)mat * 16384 + (((kstep << 3) + ntile) * 64 + lane) * 8) =
            make_uint4(o[0], o[1], o[2], o[3]);
    } else if (t < 13312) {
        const int r = t - 12288;
        const int kstep = r >> 9;
        const int ntile = (r >> 6) & 7;
        const int lane = r & 63;
        const int kbase = kstep * 32 + ((lane >> 4) << 3);
        const int n = ntile * 16 + (lane & 15);
        unsigned int o[4];
#pragma unroll
        for (int jj = 0; jj < 4; ++jj)
            o[jj] = pack2(encW[(kbase + 2 * jj) * HID + n], encW[(kbase + 2 * jj + 1) * HID + n]);
        *(uint4*)(wpe + (((kstep << 3) + ntile) * 64 + lane) * 8) =
            make_uint4(o[0], o[1], o[2], o[3]);
    } else {
        const int r = t - 13312;                    // 0..3071
        const int l = r >> 10;
        const int rr = r & 1023;
        const int kp = rr >> 7, f = rr & 127;
        const float a = eW[(l * EDGE_DIM + 2 * kp) * HID + f];
        const float b = eW[(l * EDGE_DIM + 2 * kp + 1) * HID + f];
        wek[r] = pkh(a, b);
    }
}

// ---------------------------------------------------------------------------
// Encoder via MFMA: hb = bf16(x @ enc_W + enc_b), reads fp32 x directly.
// ---------------------------------------------------------------------------
__global__ __launch_bounds__(256, 3) void k_encm(const float* __restrict__ x,
                                                 const unsigned short* __restrict__ wpe,
                                                 const float* __restrict__ b,
                                                 unsigned short* __restrict__ hb) {
    const int tid = threadIdx.x;
    const int w = tid >> 6, lane = tid & 63;
    const int q = lane >> 4, l15 = lane & 15;
    const int row0 = blockIdx.x * 64 + w * 16;
    const int ar = min(row0 + l15, N_NODES - 1);
    const float* xp = x + (size_t)ar * F_IN + q * 8;
    f32x4 acc[8];
#pragma unroll
    for (int nt = 0; nt < 8; ++nt) acc[nt] = (f32x4){0.f, 0.f, 0.f, 0.f};
#pragma unroll
    for (int ks = 0; ks < 2; ++ks) {
        const float4 v0 = *(const float4*)(xp + ks * 32);
        const float4 v1 = *(const float4*)(xp + ks * 32 + 4);
        unsigned int u[4] = {pack2(v0.x, v0.y), pack2(v0.z, v0.w),
                             pack2(v1.x, v1.y), pack2(v1.z, v1.w)};
        short8 a; __builtin_memcpy(&a, u, 16);
#pragma unroll
        for (int nt = 0; nt < 8; ++nt) {
            const short8 bf = *(const short8*)(wpe + (((ks << 3) + nt) * 64 + lane) * 8);
            acc[nt] = __builtin_amdgcn_mfma_f32_16x16x32_bf16(a, bf, acc[nt], 0, 0, 0);
        }
    }
    const int rowb = row0 + q * 4;
#pragma unroll
    for (int nt = 0; nt < 8; ++nt) {
        const float bias = b[nt * 16 + l15];
        const int cc = nt * 16 + l15;
#pragma unroll
        for (int reg = 0; reg < 4; ++reg) {
            const int r = rowb + reg;
            if (r < N_NODES)
                hb[(size_t)r * HID + cc] = (unsigned short)f2bf(acc[nt][reg] + bias);
        }
    }
}

// ---------------------------------------------------------------------------
// GINE aggregation v9: one wave per node (12500 blocks), BN+ReLU of the
// PREVIOUS layer fused via per-lane affine (sc, sh, rlo):
//   h = max(fma(raw, sc, sh), rlo); rlo = 0 (bn mode) or -inf (identity).
// z[n] = h[n] + sum relu(h[src] + attr.We + be).  f16 dot2 edge-MLP,
// chunk-of-4, depth-2 gather pipeline pinned with sched_barrier(0).
// ---------------------------------------------------------------------------
__global__ __launch_bounds__(256, 2) void k_agg(const unsigned int* __restrict__ in32,
                                                const int* __restrict__ src_s,
                                                const uint4* __restrict__ eattr_h,
                                                const unsigned int* __restrict__ wek,
                                                const float* __restrict__ be,
                                                const int* __restrict__ row_ptr,
                                                const float* __restrict__ bnst,
                                                const float* __restrict__ gamma,
                                                const float* __restrict__ beta,
                                                const int bnmode,
                                                unsigned int* __restrict__ zb32) {
    const int lane = threadIdx.x & 63;
    const int wv = threadIdx.x >> 6;
    const int f2 = lane * 2;
    half2v wx[8], wy[8];
#pragma unroll
    for (int j = 0; j < 8; ++j) {
        wx[j] = u2h(wek[j * 128 + f2]);
        wy[j] = u2h(wek[j * 128 + f2 + 1]);
    }
    const float2 eb = *(const float2*)&be[f2];

    // fused BN(prev layer)+ReLU affine
    float2 sc = make_float2(1.f, 1.f), sh = make_float2(0.f, 0.f);
    float rlo = -3.4e38f;
    if (bnmode) {
        const float invN = 1.0f / (float)N_NODES;
        const float m0 = bnst[f2] * invN, m1 = bnst[f2 + 1] * invN;
        const float v0 = fmaxf(bnst[128 + f2] * invN - m0 * m0, 0.f);
        const float v1 = fmaxf(bnst[128 + f2 + 1] * invN - m1 * m1, 0.f);
        const float r0 = rsqrtf(v0 + BN_EPS), r1 = rsqrtf(v1 + BN_EPS);
        sc = make_float2(gamma[f2] * r0, gamma[f2 + 1] * r1);
        sh = make_float2(fmaf(-m0, sc.x, beta[f2]), fmaf(-m1, sc.y, beta[f2 + 1]));
        rlo = 0.f;
    }

    const int n = blockIdx.x * 4 + wv;        // grid exact: 12500*4 = 50000
    const int base = __builtin_amdgcn_readfirstlane(row_ptr[n]);
    const int deg = __builtin_amdgcn_readfirstlane(row_ptr[n + 1]) - base;

    const unsigned int uself = in32[n * 64 + lane];
    float2 acc = make_float2(fmaxf(fmaf(bfl(uself), sc.x, sh.x), rlo),
                             fmaxf(fmaf(bfh(uself), sc.y, sh.y), rlo));

    if (deg > 0) {
        const int* sp = src_s + base;
        const uint4* ep = eattr_h + (size_t)base * 2;
        const int last = deg - 1;
        const int nch = (deg + 3) >> 2;

        unsigned int huC[4], huN[4];
        uint4 eaC[4][2], eaN[4][2];
        int s2[4];
        {
            int s0[4], s1[4];
#pragma unroll
            for (int j = 0; j < 4; ++j) s0[j] = sp[min(j, last)];
#pragma unroll
            for (int j = 0; j < 4; ++j) huC[j] = in32[s0[j] * 64 + lane];
#pragma unroll
            for (int j = 0; j < 4; ++j) s1[j] = sp[min(4 + j, last)];
            if (nch > 1) {
#pragma unroll
                for (int j = 0; j < 4; ++j) huN[j] = in32[s1[j] * 64 + lane];
            } else {
#pragma unroll
                for (int j = 0; j < 4; ++j) huN[j] = 0u;
            }
#pragma unroll
            for (int j = 0; j < 4; ++j) {
                const int e = min(j, last);
                eaC[j][0] = ep[e * 2]; eaC[j][1] = ep[e * 2 + 1];
            }
#pragma unroll
            for (int j = 0; j < 4; ++j) s2[j] = sp[min(8 + j, last)];
        }
        for (int c = 0; c < nch; ++c) {
            // ---- issue section: gathers for c+2, srcs for c+3, attrs c+1 ----
            unsigned int huNN[4] = {0u, 0u, 0u, 0u};
            if (c + 2 < nch) {
#pragma unroll
                for (int j = 0; j < 4; ++j) huNN[j] = in32[s2[j] * 64 + lane];
            }
            int s3[4];
#pragma unroll
            for (int j = 0; j < 4; ++j) s3[j] = sp[min((c + 3) * 4 + j, last)];
            if (c + 1 < nch) {
#pragma unroll
                for (int j = 0; j < 4; ++j) {
                    const int e = min((c + 1) * 4 + j, last);
                    eaN[j][0] = ep[e * 2]; eaN[j][1] = ep[e * 2 + 1];
                }
            }
            // pin: keep the issue section ABOVE the compute section
            __builtin_amdgcn_sched_barrier(0);
            // ---- compute chunk c ----
            const int rem = deg - c * 4;
#pragma unroll
            for (int j = 0; j < 4; ++j) {
                if (j < rem) {
                    const unsigned int* au = (const unsigned int*)&eaC[j][0];
                    float ex = eb.x, ey = eb.y;
#pragma unroll
                    for (int k = 0; k < 8; ++k) {
                        const half2v a = u2h(au[k]);
                        ex = __builtin_amdgcn_fdot2(a, wx[k], ex, false);
                        ey = __builtin_amdgcn_fdot2(a, wy[k], ey, false);
                    }
                    const float hx = fmaxf(fmaf(bfl(huC[j]), sc.x, sh.x), rlo);
                    const float hy = fmaxf(fmaf(bfh(huC[j]), sc.y, sh.y), rlo);
                    acc.x += fmaxf(hx + ex, 0.f);
                    acc.y += fmaxf(hy + ey, 0.f);
                }
            }
            // rotate pipeline
            if (c + 1 < nch) {
#pragma unroll
                for (int j = 0; j < 4; ++j) {
                    huC[j] = huN[j]; huN[j] = huNN[j];
                    eaC[j][0] = eaN[j][0]; eaC[j][1] = eaN[j][1];
                    s2[j] = s3[j];
                }
            }
        }
    }
    zb32[n * 64 + lane] = pack2(acc.x, acc.y);
}

// ---------------------------------------------------------------------------
// Fused node MLP via bf16 MFMA (16x16x32): z2b = bf16(relu(z@W1+b1)@W2+b2),
// plus BN sum/sumsq partials (fp32, from accumulators).
// ---------------------------------------------------------------------------
#define Z1LD 136

__global__ __launch_bounds__(256, 3) void k_mlp(const unsigned short* __restrict__ zb,
                                                const unsigned short* __restrict__ w1p,
                                                const float* __restrict__ b1,
                                                const unsigned short* __restrict__ w2p,
                                                const float* __restrict__ b2,
                                                unsigned short* __restrict__ z2b,
                                                float* __restrict__ bn) {
    __shared__ unsigned short z1s[64 * Z1LD];
    __shared__ float redA[512];
    __shared__ float redB[512];
    const int tid = threadIdx.x;
    const int w = tid >> 6, lane = tid & 63;
    const int q = lane >> 4, l15 = lane & 15;
    const int row0 = blockIdx.x * 64 + w * 16;

    const int ar = min(row0 + l15, N_NODES - 1);
    const unsigned short* aptr = zb + (size_t)ar * HID + q * 8;

    f32x4 acc[8];
#pragma unroll
    for (int nt = 0; nt < 8; ++nt) acc[nt] = (f32x4){0.f, 0.f, 0.f, 0.f};

#pragma unroll
    for (int ks = 0; ks < 4; ++ks) {
        const short8 a = *(const short8*)(aptr + ks * 32);
#pragma unroll
        for (int nt = 0; nt < 8; ++nt) {
            const short8 b = *(const short8*)(w1p + (((ks << 3) + nt) * 64 + lane) * 8);
            acc[nt] = __builtin_amdgcn_mfma_f32_16x16x32_bf16(a, b, acc[nt], 0, 0, 0);
        }
    }
    {
        const int lr0 = w * 16 + q * 4;
#pragma unroll
        for (int nt = 0; nt < 8; ++nt) {
            const float bias = b1[nt * 16 + l15];
            const int cc = nt * 16 + l15;
#pragma unroll
            for (int reg = 0; reg < 4; ++reg) {
                const float v = fmaxf(acc[nt][reg] + bias, 0.f);
                z1s[(lr0 + reg) * Z1LD + cc] = (unsigned short)f2bf(v);
            }
        }
    }
#pragma unroll
    for (int nt = 0; nt < 8; ++nt) acc[nt] = (f32x4){0.f, 0.f, 0.f, 0.f};
    const unsigned short* a2p = &z1s[(w * 16 + l15) * Z1LD + q * 8];
#pragma unroll
    for (int ks = 0; ks < 4; ++ks) {
        const short8 a = *(const short8*)(a2p + ks * 32);
#pragma unroll
        for (int nt = 0; nt < 8; ++nt) {
            const short8 b = *(const short8*)(w2p + (((ks << 3) + nt) * 64 + lane) * 8);
            acc[nt] = __builtin_amdgcn_mfma_f32_16x16x32_bf16(a, b, acc[nt], 0, 0, 0);
        }
    }
    float s[8], sq[8];
    const int rowb = row0 + q * 4;
#pragma unroll
    for (int nt = 0; nt < 8; ++nt) {
        const float bias = b2[nt * 16 + l15];
        const int cc = nt * 16 + l15;
        float ls = 0.f, lq = 0.f;
#pragma unroll
        for (int reg = 0; reg < 4; ++reg) {
            const int r = rowb + reg;
            const float v = acc[nt][reg] + bias;
            if (r < N_NODES) {
                z2b[(size_t)r * HID + cc] = (unsigned short)f2bf(v);
                ls += v;
                lq = fmaf(v, v, lq);
            }
        }
        s[nt] = ls; sq[nt] = lq;
    }
#pragma unroll
    for (int nt = 0; nt < 8; ++nt) {
        s[nt] += __shfl_xor(s[nt], 16, 64);
        s[nt] += __shfl_xor(s[nt], 32, 64);
        sq[nt] += __shfl_xor(sq[nt], 16, 64);
        sq[nt] += __shfl_xor(sq[nt], 32, 64);
    }
    if (lane < 16) {
#pragma unroll
        for (int nt = 0; nt < 8; ++nt) {
            redA[w * 128 + nt * 16 + lane] = s[nt];
            redB[w * 128 + nt * 16 + lane] = sq[nt];
        }
    }
    __syncthreads();
    if (tid < 128) {
        float t = redA[tid] + redA[128 + tid] + redA[256 + tid] + redA[384 + tid];
        atomicAdd(&bn[tid], t);
    } else {
        const int c = tid - 128;
        float t = redB[c] + redB[128 + c] + redB[256 + c] + redB[384 + c];
        atomicAdd(&bn[128 + c], t);
    }
}

// ---------------------------------------------------------------------------
// Global add pool (batch sorted), with fused BN+ReLU of the last layer.
// ---------------------------------------------------------------------------
__global__ void k_pool(const unsigned short* __restrict__ z2b, const int* __restrict__ batch,
                       const float* __restrict__ bnst, const float* __restrict__ gamma,
                       const float* __restrict__ beta, float* __restrict__ g) {
    const int f = threadIdx.x;            // 128 threads
    const float invN = 1.0f / (float)N_NODES;
    const float m = bnst[f] * invN;
    const float var = fmaxf(bnst[128 + f] * invN - m * m, 0.f);
    const float r = rsqrtf(var + BN_EPS);
    const float sc = gamma[f] * r;
    const float sh = fmaf(-m, sc, beta[f]);

    const int n0 = blockIdx.x * 128;
    const int nend = min(n0 + 128, N_NODES);
    float acc = 0.f;
    int cur = batch[n0];
    for (int n = n0; n < nend; ++n) {
        const int bb = batch[n];
        if (bb != cur) {
            atomicAdd(&g[cur * HID + f], acc);
            acc = 0.f;
            cur = bb;
        }
        const float raw = bfl((unsigned int)z2b[n * HID + f]);
        acc += fmaxf(fmaf(raw, sc, sh), 0.f);
    }
    atomicAdd(&g[cur * HID + f], acc);
}

// ---------------------------------------------------------------------------
// Head
// ---------------------------------------------------------------------------
__global__ void k_head1(const float* __restrict__ g, const float* __restrict__ W,
                        const float* __restrict__ b, float* __restrict__ g1) {
    const int idx = blockIdx.x * 256 + threadIdx.x;   // 32*256 = 8192
    const int r = idx >> 7, c = idx & 127;
    float acc = b[c];
    for (int k = 0; k < 128; ++k) acc = fmaf(g[r * HID + k], W[k * HID + c], acc);
    g1[idx] = fmaxf(acc, 0.f);
}

__global__ void k_head2(const float* __restrict__ g1, const float* __restrict__ W,
                        const float* __restrict__ b, float* __restrict__ out) {
    const int idx = threadIdx.x;          // 128
    const int r = idx >> 1, c = idx & 1;
    float acc = b[c];
    for (int k = 0; k < 128; ++k) acc = fmaf(g1[r * HID + k], W[k * 2 + c], acc);
    out[idx] = acc;
}

// ---------------------------------------------------------------------------
// Launch
// ---------------------------------------------------------------------------
extern "C" void kernel_launch(void* const* d_in, const int* in_sizes, int n_in,
                              void* d_out, int out_size, void* d_ws, size_t ws_size,
                              hipStream_t stream) {
    const float* x     = (const float*)d_in[0];
    const int*   ei    = (const int*)d_in[1];
    const float* eattr = (const float*)d_in[2];
    const int*   batch = (const int*)d_in[3];
    const float* encW  = (const float*)d_in[4];
    const float* encb  = (const float*)d_in[5];
    const float* eW    = (const float*)d_in[6];
    const float* eb    = (const float*)d_in[7];
    const float* W1    = (const float*)d_in[8];
    const float* b1    = (const float*)d_in[9];
    const float* W2    = (const float*)d_in[10];
    const float* b2    = (const float*)d_in[11];
    const float* gam   = (const float*)d_in[12];
    const float* bet   = (const float*)d_in[13];
    const float* hW1   = (const float*)d_in[14];
    const float* hb1   = (const float*)d_in[15];
    const float* hW2   = (const float*)d_in[16];
    const float* hb2   = (const float*)d_in[17];
    float* out = (float*)d_out;

    // workspace layout (float-sized slots)
    float* ws = (float*)d_ws;
    unsigned short* z2b = (unsigned short*)ws;              // 6.4M u16 = 3.2M floats
    float* bn  = ws + 3200000;              // 256
    float* g   = ws + 3200256;              // 8,192
    float* g1  = ws + 3208448;              // 8,192
    unsigned short* hb = (unsigned short*)(ws + 3216640);   // 6.4M u16
    unsigned int* zb32 = (unsigned int*)(ws + 6416640);     // 6.4M u16
    int* row_ptr = (int*)(ws + 11216640);   // 50,001
    int* cursor  = row_ptr + N_NODES + 1;   // 50,000
    int* elist   = cursor + N_NODES;        // 640,000
    int* bsums   = elist + N_EDGES;         // 256
    int* src_s   = bsums + 256;             // 640,000
    uint4* eattr_h = (uint4*)(ws + 12596900);               // 5.12M u32
    unsigned short* wp  = (unsigned short*)(ws + 17716900); // 98,304 u16
    unsigned short* wpe = (unsigned short*)(ws + 17766100); // 8,192 u16
    unsigned int*   wek = (unsigned int*)(ws + 17770200);   // 3,072 u32

    const int* esrc = ei;
    const int* edst = ei + N_EDGES;

    // CSR build + edge materialization (per call)
    hipMemsetAsync(row_ptr, 0, (N_NODES + 1) * sizeof(int), stream);
    k_hist<<<N_EDGES / 256, 256, 0, stream>>>(edst, row_ptr);
    k_blockred<<<196, 256, 0, stream>>>(row_ptr, bsums);
    k_scan_bsums<<<1, 256, 0, stream>>>(bsums, 196);
    k_scan_blocks<<<196, 256, 0, stream>>>(row_ptr, bsums, cursor);
    k_fill<<<N_EDGES / 256, 256, 0, stream>>>(edst, cursor, elist);
    k_gather<<<N_EDGES / 1024, 256, 0, stream>>>(elist, esrc, eattr, src_s, eattr_h);

    // merged weight packing
    k_pack<<<64, 256, 0, stream>>>(W1, W2, encW, eW, wp, wpe, wek);

    // encoder -> bf16 h (MFMA, reads fp32 x directly)
    k_encm<<<782, 256, 0, stream>>>(x, wpe, encb, hb);

    for (int l = 0; l < N_LAYERS; ++l) {
        const unsigned int* in32 = (l == 0) ? (const unsigned int*)hb
                                            : (const unsigned int*)z2b;
        k_agg<<<12500, 256, 0, stream>>>(in32, src_s, eattr_h,
                                         wek + l * 1024, eb + l * HID, row_ptr,
                                         bn, gam + (l ? (l - 1) * HID : 0),
                                         bet + (l ? (l - 1) * HID : 0),
                                         (l > 0) ? 1 : 0, zb32);
        hipMemsetAsync(bn, 0, 256 * sizeof(float), stream);
        k_mlp<<<782, 256, 0, stream>>>((const unsigned short*)zb32,
                                       wp + (size_t)l * 16384, b1 + l * HID,
                                       wp + (size_t)(3 + l) * 16384, b2 + l * HID,
                                       z2b, bn);
    }

    hipMemsetAsync(g, 0, NUM_GRAPHS * HID * sizeof(float), stream);
    k_pool<<<391, 128, 0, stream>>>(z2b, batch, bn, gam + 2 * HID, bet + 2 * HID, g);
    k_head1<<<32, 256, 0, stream>>>(g, hW1, hb1, g1);
    k_head2<<<1, 128, 0, stream>>>(g1, hW2, hb2, out);
}